// Round 3
// baseline (4417.334 us; speedup 1.0000x reference)
//
#include <hip/hip_runtime.h>

#define NLAYERS 6
#define BSZ 16
#define NQL 300
#define DM 256
#define NHEAD 8
#define HDIM 32
#define NLVL 3
#define NPT 4
#define DFFN 1024
#define NCLS 80
#define LVTOT 8400
#define NROW (BSZ * NQL)   // 4800

typedef __attribute__((ext_vector_type(8))) short bf16x8;
typedef __attribute__((ext_vector_type(8))) ushort us8;
typedef __attribute__((ext_vector_type(4))) float f32x4;

__device__ __forceinline__ float b2f(ushort u) {
    return __uint_as_float(((uint)u) << 16);
}
__device__ __forceinline__ ushort f2b(float f) {
    uint i = __float_as_uint(f);
    uint r = i + 0x7fffu + ((i >> 16) & 1u);   // RNE
    return (ushort)(r >> 16);
}
__device__ __forceinline__ void split2(float v, ushort& h, ushort& l) {
    ushort hh = f2b(v);
    h = hh;
    l = f2b(v - b2f(hh));
}
__device__ __forceinline__ void store_out(float* p, float v) { *p = v; }
__device__ __forceinline__ void store_out(ushort* p, float v) { *p = f2b(v); }

// ---------------------------------------------------------------------------
// Batched transpose + bf16 hi/lo split: src fp32 (B,K,N) -> dst_hi/dst_lo (B,N,K)
// ---------------------------------------------------------------------------
__global__ __launch_bounds__(256) void transpose_split_kernel(
    const float* __restrict__ src, ushort* __restrict__ dh,
    ushort* __restrict__ dl, int K, int N)
{
    __shared__ float tile[32][33];
    const size_t zoff = (size_t)blockIdx.z * (size_t)K * (size_t)N;
    src += zoff; dh += zoff; dl += zoff;
    const int n0 = blockIdx.x * 32, k0 = blockIdx.y * 32;
    const int tx = threadIdx.x, ty = threadIdx.y;   // 32 x 8
    for (int r = 0; r < 32; r += 8) {
        int k = k0 + ty + r, n = n0 + tx;
        if (k < K && n < N) tile[ty + r][tx] = src[(size_t)k * N + n];
    }
    __syncthreads();
    for (int r = 0; r < 32; r += 8) {
        int n = n0 + ty + r, k = k0 + tx;
        if (n < N && k < K) {
            ushort h, l;
            split2(tile[tx][ty + r], h, l);
            dh[(size_t)n * K + k] = h;
            dl[(size_t)n * K + k] = l;
        }
    }
}

// ---------------------------------------------------------------------------
// Split-bf16 MFMA GEMM: C[M,N] = act(A[M,K] @ B[K,N] + bias)
// A fp32; B provided transposed & pre-split: BTh/BTl are (N x K) bf16 planes.
// D = Ah*Bh + Al*Bh + Ah*Bl (fp32 accum) ~ fp32 precision.
// Block 256 thr = 4 waves, 64x64 tile. M % 64 == 0.
// ---------------------------------------------------------------------------
template <int ACT, typename TOUT>
__global__ __launch_bounds__(256) void gemm_sp(
    const float* __restrict__ A, const ushort* __restrict__ BTh,
    const ushort* __restrict__ BTl, const float* __restrict__ bias,
    TOUT* __restrict__ C, int M, int N, int K)
{
    __shared__ ushort Ah[64 * 40];
    __shared__ ushort Al[64 * 40];
    __shared__ ushort Bh[64 * 40];
    __shared__ ushort Bl[64 * 40];

    const int tid  = threadIdx.x;
    const int m0   = blockIdx.x * 64;
    const int n0   = blockIdx.y * 64;
    const int wv   = tid >> 6;
    const int lane = tid & 63;
    const int lm   = lane & 15;
    const int lq   = lane >> 4;
    const int r    = tid >> 2;
    const int c8   = (tid & 3) * 8;

    f32x4 acc[4] = {};

    for (int k0 = 0; k0 < K; k0 += 32) {
        __syncthreads();
        // ---- stage A (fp32 -> hi/lo bf16) ----
        {
            float av[8];
            if (k0 + 32 <= K) {
                *(float4*)&av[0] = *(const float4*)&A[(size_t)(m0 + r) * K + k0 + c8];
                *(float4*)&av[4] = *(const float4*)&A[(size_t)(m0 + r) * K + k0 + c8 + 4];
            } else {
#pragma unroll
                for (int j = 0; j < 8; ++j) {
                    int k = k0 + c8 + j;
                    av[j] = (k < K) ? A[(size_t)(m0 + r) * K + k] : 0.f;
                }
            }
            us8 hv, lv;
#pragma unroll
            for (int j = 0; j < 8; ++j) {
                ushort h, l;
                split2(av[j], h, l);
                hv[j] = h; lv[j] = l;
            }
            *(us8*)&Ah[r * 40 + c8] = hv;
            *(us8*)&Al[r * 40 + c8] = lv;
        }
        // ---- stage B (pre-split bf16 planes) ----
        if (n0 + r < N && k0 + 32 <= K) {
            *(uint4*)&Bh[r * 40 + c8] = *(const uint4*)&BTh[(size_t)(n0 + r) * K + k0 + c8];
            *(uint4*)&Bl[r * 40 + c8] = *(const uint4*)&BTl[(size_t)(n0 + r) * K + k0 + c8];
        } else if (n0 + r < N) {
#pragma unroll
            for (int j = 0; j < 8; ++j) {
                int k = k0 + c8 + j;
                Bh[r * 40 + c8 + j] = (k < K) ? BTh[(size_t)(n0 + r) * K + k] : (ushort)0;
                Bl[r * 40 + c8 + j] = (k < K) ? BTl[(size_t)(n0 + r) * K + k] : (ushort)0;
            }
        } else {
            uint4 z = {0, 0, 0, 0};
            *(uint4*)&Bh[r * 40 + c8] = z;
            *(uint4*)&Bl[r * 40 + c8] = z;
        }
        __syncthreads();

        bf16x8 afh = *(const bf16x8*)&Ah[(wv * 16 + lm) * 40 + lq * 8];
        bf16x8 afl = *(const bf16x8*)&Al[(wv * 16 + lm) * 40 + lq * 8];
#pragma unroll
        for (int nb = 0; nb < 4; ++nb) {
            bf16x8 bfh = *(const bf16x8*)&Bh[(nb * 16 + lm) * 40 + lq * 8];
            bf16x8 bfl = *(const bf16x8*)&Bl[(nb * 16 + lm) * 40 + lq * 8];
            acc[nb] = __builtin_amdgcn_mfma_f32_16x16x32_bf16(afh, bfh, acc[nb], 0, 0, 0);
            acc[nb] = __builtin_amdgcn_mfma_f32_16x16x32_bf16(afl, bfh, acc[nb], 0, 0, 0);
            acc[nb] = __builtin_amdgcn_mfma_f32_16x16x32_bf16(afh, bfl, acc[nb], 0, 0, 0);
        }
    }

    const int row = m0 + wv * 16 + lq * 4;
#pragma unroll
    for (int nb = 0; nb < 4; ++nb) {
        int col = n0 + nb * 16 + lm;
        if (col < N) {
            float bv = bias ? bias[col] : 0.f;
#pragma unroll
            for (int rr = 0; rr < 4; ++rr) {
                float v = acc[nb][rr] + bv;
                if (ACT) v = fmaxf(v, 0.f);
                store_out(&C[(size_t)(row + rr) * N + col], v);
            }
        }
    }
}

// ---------------------------------------------------------------------------
// MHA: one wave per (b, h, q). qh/kh/vh fp32 (b, q, h*32+d). out fp32.
// ---------------------------------------------------------------------------
__global__ __launch_bounds__(256) void mha_kernel(
    const float* __restrict__ qh, const float* __restrict__ kh,
    const float* __restrict__ vh, float* __restrict__ outp)
{
    __shared__ float sc[4][304];
    __shared__ float qv[4][32];
    const int wv = threadIdx.x >> 6, lane = threadIdx.x & 63;
    const int gw = blockIdx.x * 4 + wv;
    const int b = gw / (NHEAD * NQL);
    const int rem = gw % (NHEAD * NQL);
    const int h = rem / NQL;
    const int q = rem % NQL;
    const size_t base = (size_t)b * NQL * DM + h * HDIM;

    if (lane < 32) qv[wv][lane] = qh[base + (size_t)q * DM + lane];
    __syncthreads();

    const float scale = 0.17677669529663687f;  // 1/sqrt(32)
    float lmax = -1e30f;
    for (int k = lane; k < NQL; k += 64) {
        const float* krow = kh + base + (size_t)k * DM;
        float s = 0.f;
#pragma unroll
        for (int j = 0; j < 32; ++j) s += qv[wv][j] * krow[j];
        s *= scale;
        sc[wv][k] = s;
        lmax = fmaxf(lmax, s);
    }
#pragma unroll
    for (int m = 32; m; m >>= 1) lmax = fmaxf(lmax, __shfl_xor(lmax, m, 64));
    __syncthreads();

    float lsum = 0.f;
    for (int k = lane; k < NQL; k += 64) {
        float p = expf(sc[wv][k] - lmax);
        sc[wv][k] = p;
        lsum += p;
    }
#pragma unroll
    for (int m = 32; m; m >>= 1) lsum += __shfl_xor(lsum, m, 64);
    const float inv = 1.f / lsum;
    __syncthreads();

    const int d = lane & 31, half = lane >> 5;
    float acc = 0.f;
    for (int k = half; k < NQL; k += 2)
        acc += sc[wv][k] * vh[base + (size_t)k * DM + d];
    acc += __shfl_xor(acc, 32, 64);
    if (lane < 32) outp[base + (size_t)q * DM + lane] = acc * inv;
}

// ---------------------------------------------------------------------------
// Deformable sampling: one block per (b, q). thread t: h=t>>5, d=t&31.
// val is bf16-hi plane of the value projection.
// ---------------------------------------------------------------------------
__global__ __launch_bounds__(256) void deform_kernel(
    const ushort* __restrict__ val, const float* __restrict__ off,
    const float* __restrict__ awl, const float* __restrict__ refd,
    float* __restrict__ outp)
{
    __shared__ float offs[192];
    __shared__ float aws[96];
    __shared__ float rr[4];
    const int row = blockIdx.x;        // b*NQL + q
    const int b = row / NQL;
    const int t = threadIdx.x;
    if (t < 192) offs[t] = off[(size_t)row * 192 + t];
    if (t < 96)  aws[t] = awl[(size_t)row * 96 + t];
    if (t < 4)   rr[t] = refd[row * 4 + t];
    __syncthreads();

    const int h = t >> 5, d = t & 31;
    float mx = -1e30f;
#pragma unroll
    for (int j = 0; j < 12; ++j) mx = fmaxf(mx, aws[h * 12 + j]);
    float ev[12]; float se = 0.f;
#pragma unroll
    for (int j = 0; j < 12; ++j) { ev[j] = expf(aws[h * 12 + j] - mx); se += ev[j]; }
    const float inv = 1.f / se;

    const int HWs[3] = {80, 40, 20};
    const int STs[3] = {0, 6400, 8000};
    float acc = 0.f;
#pragma unroll
    for (int l = 0; l < NLVL; ++l) {
        const int Wd = HWs[l], Hd = HWs[l], st = STs[l];
#pragma unroll
        for (int p = 0; p < NPT; ++p) {
            const float w12 = ev[l * 4 + p] * inv;
            const float ox = offs[((h * 3 + l) * 4 + p) * 2 + 0];
            const float oy = offs[((h * 3 + l) * 4 + p) * 2 + 1];
            const float x = (rr[0] + ox * 0.125f * rr[2]) * Wd - 0.5f;
            const float y = (rr[1] + oy * 0.125f * rr[3]) * Hd - 0.5f;
            const float xf = floorf(x), yf = floorf(y);
            const int x0 = (int)xf, y0 = (int)yf;
            const float wx = x - xf, wy = y - yf;
            const float tw[4] = {(1 - wx) * (1 - wy), wx * (1 - wy),
                                 (1 - wx) * wy,       wx * wy};
            const int xs[4] = {x0, x0 + 1, x0, x0 + 1};
            const int ys[4] = {y0, y0, y0 + 1, y0 + 1};
            float sv = 0.f;
#pragma unroll
            for (int tp = 0; tp < 4; ++tp) {
                const int xi = xs[tp], yi = ys[tp];
                if (xi >= 0 && xi < Wd && yi >= 0 && yi < Hd) {
                    const int idx = st + yi * Wd + xi;
                    sv += tw[tp] * b2f(val[((size_t)b * LVTOT + idx) * DM + h * HDIM + d]);
                }
            }
            acc += w12 * sv;
        }
    }
    outp[(size_t)row * DM + t] = acc;
}

// ---------------------------------------------------------------------------
// Fused residual add + LayerNorm (fp32). One wave per row.
// Optionally writes q2 = LN(x+dl) + qpos.
// ---------------------------------------------------------------------------
__global__ __launch_bounds__(256) void addln_kernel(
    const float* x, const float* __restrict__ dl,
    const float* __restrict__ g, const float* __restrict__ bb,
    float* outf, const float* __restrict__ qpos, float* __restrict__ q2)
{
    const int wv = threadIdx.x >> 6, lane = threadIdx.x & 63;
    const int row = blockIdx.x * 4 + wv;
    const size_t base = (size_t)row * DM + lane * 4;
    const float4 xv = *(const float4*)(x + base);
    const float4 dv = *(const float4*)(dl + base);
    float v[4] = {xv.x + dv.x, xv.y + dv.y, xv.z + dv.z, xv.w + dv.w};

    float s = v[0] + v[1] + v[2] + v[3];
#pragma unroll
    for (int m = 32; m; m >>= 1) s += __shfl_xor(s, m, 64);
    const float mean = s * (1.f / 256.f);
    float sq = 0.f;
#pragma unroll
    for (int j = 0; j < 4; ++j) { float dd = v[j] - mean; sq += dd * dd; }
#pragma unroll
    for (int m = 32; m; m >>= 1) sq += __shfl_xor(sq, m, 64);
    const float rstd = rsqrtf(sq * (1.f / 256.f) + 1e-5f);

    float y[4];
#pragma unroll
    for (int j = 0; j < 4; ++j) {
        const int col = lane * 4 + j;
        y[j] = (v[j] - mean) * rstd * g[col] + bb[col];
    }
    *(float4*)(outf + base) = make_float4(y[0], y[1], y[2], y[3]);
    if (q2) {
        const float4 qp = *(const float4*)(qpos + base);
        *(float4*)(q2 + base) = make_float4(y[0] + qp.x, y[1] + qp.y,
                                            y[2] + qp.z, y[3] + qp.w);
    }
}

// ---------------------------------------------------------------------------
// Small elementwise kernels
// ---------------------------------------------------------------------------
__global__ __launch_bounds__(256) void init_ref_kernel(
    const float* __restrict__ rpu, float* __restrict__ refd, int n)
{
    int i = blockIdx.x * 256 + threadIdx.x;
    if (i < n) refd[i] = 1.f / (1.f + expf(-rpu[i]));
}

__global__ __launch_bounds__(256) void prep_kernel(
    const float* __restrict__ outf, const float* __restrict__ qpos,
    float* __restrict__ qf, int n)
{
    int i = blockIdx.x * 256 + threadIdx.x;
    if (i < n) qf[i] = outf[i] + qpos[i];
}

__global__ __launch_bounds__(256) void refupd_kernel(
    const float* __restrict__ b3, float* __restrict__ refd,
    float* __restrict__ dout, int writeout)
{
    int i = blockIdx.x * 256 + threadIdx.x;
    if (i < NROW * 4) {
        float r = fminf(fmaxf(refd[i], 0.f), 1.f);
        float invs = logf(fmaxf(r, 1e-5f)) - logf(fmaxf(1.f - r, 1e-5f));
        float v = 1.f / (1.f + expf(-(b3[i] + invs)));
        refd[i] = v;
        if (writeout) dout[i] = v;
    }
}

// ---------------------------------------------------------------------------
// Host launch
// ---------------------------------------------------------------------------
extern "C" void kernel_launch(void* const* d_in, const int* in_sizes, int n_in,
                              void* d_out, int out_size, void* d_ws, size_t ws_size,
                              hipStream_t stream)
{
    const float* tgt    = (const float*)d_in[0];
    const float* rpu    = (const float*)d_in[1];
    const float* memory = (const float*)d_in[2];
    const float* Wq  = (const float*)d_in[5];  const float* bq  = (const float*)d_in[6];
    const float* Wk  = (const float*)d_in[7];  const float* bk  = (const float*)d_in[8];
    const float* Wv  = (const float*)d_in[9];  const float* bv  = (const float*)d_in[10];
    const float* Wo  = (const float*)d_in[11]; const float* bo  = (const float*)d_in[12];
    const float* ln1g = (const float*)d_in[13]; const float* ln1b = (const float*)d_in[14];
    const float* ln2g = (const float*)d_in[15]; const float* ln2b = (const float*)d_in[16];
    const float* ln3g = (const float*)d_in[17]; const float* ln3b = (const float*)d_in[18];
    const float* Wvp = (const float*)d_in[19]; const float* bvp = (const float*)d_in[20];
    const float* Woff = (const float*)d_in[21]; const float* boff = (const float*)d_in[22];
    const float* Waw = (const float*)d_in[23]; const float* baw = (const float*)d_in[24];
    const float* Wop = (const float*)d_in[25]; const float* bop = (const float*)d_in[26];
    const float* Wff1 = (const float*)d_in[27]; const float* bff1 = (const float*)d_in[28];
    const float* Wff2 = (const float*)d_in[29]; const float* bff2 = (const float*)d_in[30];
    const float* Wb1 = (const float*)d_in[31]; const float* bb1 = (const float*)d_in[32];
    const float* Wb2 = (const float*)d_in[33]; const float* bb2 = (const float*)d_in[34];
    const float* Wb3 = (const float*)d_in[35]; const float* bb3 = (const float*)d_in[36];
    const float* Ws  = (const float*)d_in[37]; const float* bs_ = (const float*)d_in[38];
    const float* Wp1 = (const float*)d_in[39]; const float* bp1 = (const float*)d_in[40];
    const float* Wp2 = (const float*)d_in[41]; const float* bp2 = (const float*)d_in[42];

    size_t off = 0;
    auto alloc = [&](size_t elems, size_t elsz) -> void* {
        void* r = (char*)d_ws + off;
        off += elems * elsz;
        off = (off + 255) & ~(size_t)255;
        return r;
    };
    // split weight planes (hi, lo), transposed to (N x K)
    auto wplane = [&](size_t els) {
        ushort* h = (ushort*)alloc(els, 2);
        ushort* l = (ushort*)alloc(els, 2);
        return (void*)nullptr, h, l;  // unused
    };
    (void)wplane;
    ushort *wqh = (ushort*)alloc(6 * 65536, 2), *wql = (ushort*)alloc(6 * 65536, 2);
    ushort *wkh = (ushort*)alloc(6 * 65536, 2), *wkl = (ushort*)alloc(6 * 65536, 2);
    ushort *wvh = (ushort*)alloc(6 * 65536, 2), *wvl = (ushort*)alloc(6 * 65536, 2);
    ushort *woh = (ushort*)alloc(6 * 65536, 2), *wol = (ushort*)alloc(6 * 65536, 2);
    ushort *wvph = (ushort*)alloc(6 * 65536, 2), *wvpl = (ushort*)alloc(6 * 65536, 2);
    ushort *woffh = (ushort*)alloc(6 * 49152, 2), *woffl = (ushort*)alloc(6 * 49152, 2);
    ushort *wawh = (ushort*)alloc(6 * 24576, 2), *wawl2 = (ushort*)alloc(6 * 24576, 2);
    ushort *woph = (ushort*)alloc(6 * 65536, 2), *wopl = (ushort*)alloc(6 * 65536, 2);
    ushort *wf1h = (ushort*)alloc(6 * 262144, 2), *wf1l = (ushort*)alloc(6 * 262144, 2);
    ushort *wf2h = (ushort*)alloc(6 * 262144, 2), *wf2l = (ushort*)alloc(6 * 262144, 2);
    ushort *wb1h = (ushort*)alloc(6 * 65536, 2), *wb1l = (ushort*)alloc(6 * 65536, 2);
    ushort *wb2h = (ushort*)alloc(6 * 65536, 2), *wb2l = (ushort*)alloc(6 * 65536, 2);
    ushort *wb3h = (ushort*)alloc(6 * 1024, 2), *wb3l = (ushort*)alloc(6 * 1024, 2);
    ushort *wsh = (ushort*)alloc(6 * 20480, 2), *wsl = (ushort*)alloc(6 * 20480, 2);
    ushort *wp1h = (ushort*)alloc(2048, 2), *wp1l = (ushort*)alloc(2048, 2);
    ushort *wp2h = (ushort*)alloc(131072, 2), *wp2l = (ushort*)alloc(131072, 2);

    ushort* val_bf = (ushort*)alloc((size_t)BSZ * LVTOT * DM, 2);   // 68.8 MB
    float*  out_f  = (float*)alloc(NROW * DM, 4);
    float*  qpos_f = (float*)alloc(NROW * DM, 4);
    float*  q_f    = (float*)alloc(NROW * DM, 4);
    float*  q2_f   = (float*)alloc(NROW * DM, 4);
    float*  tmp_f  = (float*)alloc(NROW * DM, 4);
    float*  b3_f   = (float*)alloc(NROW * 4, 4);
    float*  refd_f = (float*)alloc(NROW * 4, 4);
    // scratch arena (lifetimes disjoint across pipeline phases)
    float* arena = (float*)alloc(NROW * 1024, 4);   // 19.7 MB
    float* t1_f  = arena;                            // 4800 x 512
    float* qh_f  = arena;                            // 4 x (4800 x 256)
    float* kh_f  = arena + NROW * DM;
    float* vh_f  = arena + 2 * NROW * DM;
    float* att_f = arena + 3 * NROW * DM;
    float* off_f = arena;                            // 4800 x 192
    float* aw_f  = arena + NROW * 192;               // 4800 x 96
    float* samp_f= arena + NROW * 288;               // 4800 x 256
    float* ff_f  = arena;                            // 4800 x 1024
    float* h1_f  = arena;                            // 4800 x 256
    float* h2_f  = arena + NROW * DM;

    if (off > ws_size) return;

    dim3 tb(32, 8);
    auto T = [&](const float* s, ushort* dh, ushort* dl, int K, int N, int B) {
        dim3 g((N + 31) / 32, (K + 31) / 32, B);
        transpose_split_kernel<<<g, tb, 0, stream>>>(s, dh, dl, K, N);
    };
    T(Wq, wqh, wql, 256, 256, 6);   T(Wk, wkh, wkl, 256, 256, 6);
    T(Wv, wvh, wvl, 256, 256, 6);   T(Wo, woh, wol, 256, 256, 6);
    T(Wvp, wvph, wvpl, 256, 256, 6); T(Woff, woffh, woffl, 256, 192, 6);
    T(Waw, wawh, wawl2, 256, 96, 6); T(Wop, woph, wopl, 256, 256, 6);
    T(Wff1, wf1h, wf1l, 256, 1024, 6); T(Wff2, wf2h, wf2l, 1024, 256, 6);
    T(Wb1, wb1h, wb1l, 256, 256, 6); T(Wb2, wb2h, wb2l, 256, 256, 6);
    T(Wb3, wb3h, wb3l, 256, 4, 6);  T(Ws, wsh, wsl, 256, 80, 6);
    T(Wp1, wp1h, wp1l, 4, 512, 1);  T(Wp2, wp2h, wp2l, 512, 256, 1);

    hipMemcpyAsync(out_f, tgt, (size_t)NROW * DM * 4, hipMemcpyDeviceToDevice, stream);
    init_ref_kernel<<<75, 256, 0, stream>>>(rpu, refd_f, NROW * 4);

    auto G = [&](const float* A, const ushort* BTh, const ushort* BTl,
                 const float* bias, float* C, int M, int N, int K, bool relu) {
        dim3 g(M / 64, (N + 63) / 64);
        if (relu) gemm_sp<1, float><<<g, 256, 0, stream>>>(A, BTh, BTl, bias, C, M, N, K);
        else      gemm_sp<0, float><<<g, 256, 0, stream>>>(A, BTh, BTl, bias, C, M, N, K);
    };

    for (int i = 0; i < NLAYERS; ++i) {
        // qpos = relu(ref_d @ Wp1 + bp1) @ Wp2 + bp2
        G(refd_f, wp1h, wp1l, bp1, t1_f, NROW, 512, 4, true);
        G(t1_f, wp2h, wp2l, bp2, qpos_f, NROW, 256, 512, false);
        prep_kernel<<<4800, 256, 0, stream>>>(out_f, qpos_f, q_f, NROW * DM);
        // MHA
        G(q_f, wqh + i * 65536, wql + i * 65536, bq + i * 256, qh_f, NROW, 256, 256, false);
        G(q_f, wkh + i * 65536, wkl + i * 65536, bk + i * 256, kh_f, NROW, 256, 256, false);
        G(out_f, wvh + i * 65536, wvl + i * 65536, bv + i * 256, vh_f, NROW, 256, 256, false);
        mha_kernel<<<9600, 256, 0, stream>>>(qh_f, kh_f, vh_f, att_f);
        G(att_f, woh + i * 65536, wol + i * 65536, bo + i * 256, tmp_f, NROW, 256, 256, false);
        addln_kernel<<<1200, 256, 0, stream>>>(out_f, tmp_f, ln1g + i * 256, ln1b + i * 256,
                                               out_f, qpos_f, q2_f);
        // Deformable attention
        {
            dim3 g((BSZ * LVTOT) / 64, 4);
            gemm_sp<0, ushort><<<g, 256, 0, stream>>>(
                memory, wvph + i * 65536, wvpl + i * 65536, bvp + i * 256,
                val_bf, BSZ * LVTOT, 256, 256);
        }
        G(q2_f, woffh + i * 49152, woffl + i * 49152, boff + i * 192, off_f, NROW, 192, 256, false);
        G(q2_f, wawh + i * 24576, wawl2 + i * 24576, baw + i * 96, aw_f, NROW, 96, 256, false);
        deform_kernel<<<4800, 256, 0, stream>>>(val_bf, off_f, aw_f, refd_f, samp_f);
        G(samp_f, woph + i * 65536, wopl + i * 65536, bop + i * 256, tmp_f, NROW, 256, 256, false);
        addln_kernel<<<1200, 256, 0, stream>>>(out_f, tmp_f, ln2g + i * 256, ln2b + i * 256,
                                               out_f, nullptr, nullptr);
        // FFN
        G(out_f, wf1h + i * 262144, wf1l + i * 262144, bff1 + i * 1024, ff_f, NROW, 1024, 256, true);
        G(ff_f, wf2h + i * 262144, wf2l + i * 262144, bff2 + i * 256, tmp_f, NROW, 256, 1024, false);
        addln_kernel<<<1200, 256, 0, stream>>>(out_f, tmp_f, ln3g + i * 256, ln3b + i * 256,
                                               out_f, nullptr, nullptr);
        // bbox head
        G(out_f, wb1h + i * 65536, wb1l + i * 65536, bb1 + i * 256, h1_f, NROW, 256, 256, true);
        G(h1_f, wb2h + i * 65536, wb2l + i * 65536, bb2 + i * 256, h2_f, NROW, 256, 256, true);
        G(h2_f, wb3h + i * 1024, wb3l + i * 1024, bb3 + i * 4, b3_f, NROW, 4, 256, false);
        refupd_kernel<<<75, 256, 0, stream>>>(b3_f, refd_f, (float*)d_out,
                                              (i == NLAYERS - 1) ? 1 : 0);
        if (i == NLAYERS - 1) {
            G(out_f, wsh + i * 20480, wsl + i * 20480, bs_ + i * 80,
              (float*)d_out + NROW * 4, NROW, 80, 256, false);
        }
    }
}

// Round 4
// 2809.282 us; speedup vs baseline: 1.5724x; 1.5724x over previous
//
#include <hip/hip_runtime.h>

#define NLAYERS 6
#define BSZ 16
#define NQL 300
#define DM 256
#define NHEAD 8
#define HDIM 32
#define NLVL 3
#define NPT 4
#define DFFN 1024
#define NCLS 80
#define LVTOT 8400
#define NROW (BSZ * NQL)   // 4800

typedef __attribute__((ext_vector_type(8))) short bf16x8;
typedef __attribute__((ext_vector_type(8))) ushort us8;
typedef __attribute__((ext_vector_type(4))) float f32x4;

__device__ __forceinline__ float b2f(ushort u) {
    return __uint_as_float(((uint)u) << 16);
}
__device__ __forceinline__ ushort f2b(float f) {
    uint i = __float_as_uint(f);
    uint r = i + 0x7fffu + ((i >> 16) & 1u);   // RNE
    return (ushort)(r >> 16);
}
__device__ __forceinline__ void split2(float v, ushort& h, ushort& l) {
    ushort hh = f2b(v);
    h = hh;
    l = f2b(v - b2f(hh));
}
__device__ __forceinline__ void store_out(float* p, float v) { *p = v; }
__device__ __forceinline__ void store_out(ushort* p, float v) { *p = f2b(v); }

// ---------------------------------------------------------------------------
// Batched transpose + bf16 hi/lo split: src fp32 (B,K,N) -> dst_hi/dst_lo (B,N,K)
// ---------------------------------------------------------------------------
__global__ __launch_bounds__(256) void transpose_split_kernel(
    const float* __restrict__ src, ushort* __restrict__ dh,
    ushort* __restrict__ dl, int K, int N)
{
    __shared__ float tile[32][33];
    const size_t zoff = (size_t)blockIdx.z * (size_t)K * (size_t)N;
    src += zoff; dh += zoff; dl += zoff;
    const int n0 = blockIdx.x * 32, k0 = blockIdx.y * 32;
    const int tx = threadIdx.x, ty = threadIdx.y;   // 32 x 8
    for (int r = 0; r < 32; r += 8) {
        int k = k0 + ty + r, n = n0 + tx;
        if (k < K && n < N) tile[ty + r][tx] = src[(size_t)k * N + n];
    }
    __syncthreads();
    for (int r = 0; r < 32; r += 8) {
        int n = n0 + ty + r, k = k0 + tx;
        if (n < N && k < K) {
            ushort h, l;
            split2(tile[tx][ty + r], h, l);
            dh[(size_t)n * K + k] = h;
            dl[(size_t)n * K + k] = l;
        }
    }
}

// ---------------------------------------------------------------------------
// Split-bf16 MFMA GEMM: C[M,N] = act(A[M,K] @ B[K,N] + bias)
// A fp32; B transposed & pre-split (BTh/BTl: N x K bf16 planes).
// SPLIT=1: D = Ah*Bh + Al*Bh + Ah*Bl (~fp32). SPLIT=0: D = Ah*Bh (bf16-grade).
// Block 256 thr = 4 waves, 64x64 tile. M % 64 == 0.
// ---------------------------------------------------------------------------
template <int ACT, int SPLIT, typename TOUT>
__global__ __launch_bounds__(256) void gemm_sp(
    const float* __restrict__ A, const ushort* __restrict__ BTh,
    const ushort* __restrict__ BTl, const float* __restrict__ bias,
    TOUT* __restrict__ C, int M, int N, int K)
{
    __shared__ ushort Ah[64 * 40];
    __shared__ ushort Al[SPLIT ? 64 * 40 : 8];
    __shared__ ushort Bh[64 * 40];
    __shared__ ushort Bl[SPLIT ? 64 * 40 : 8];

    const int tid  = threadIdx.x;
    const int m0   = blockIdx.x * 64;
    const int n0   = blockIdx.y * 64;
    const int wv   = tid >> 6;
    const int lane = tid & 63;
    const int lm   = lane & 15;
    const int lq   = lane >> 4;
    const int r    = tid >> 2;
    const int c8   = (tid & 3) * 8;

    f32x4 acc[4] = {};

    for (int k0 = 0; k0 < K; k0 += 32) {
        __syncthreads();
        // ---- stage A (fp32 -> hi/lo bf16) ----
        {
            float av[8];
            if (k0 + 32 <= K) {
                *(float4*)&av[0] = *(const float4*)&A[(size_t)(m0 + r) * K + k0 + c8];
                *(float4*)&av[4] = *(const float4*)&A[(size_t)(m0 + r) * K + k0 + c8 + 4];
            } else {
#pragma unroll
                for (int j = 0; j < 8; ++j) {
                    int k = k0 + c8 + j;
                    av[j] = (k < K) ? A[(size_t)(m0 + r) * K + k] : 0.f;
                }
            }
            us8 hv, lv;
#pragma unroll
            for (int j = 0; j < 8; ++j) {
                ushort h, l;
                split2(av[j], h, l);
                hv[j] = h; lv[j] = l;
            }
            *(us8*)&Ah[r * 40 + c8] = hv;
            if (SPLIT) *(us8*)&Al[r * 40 + c8] = lv;
        }
        // ---- stage B ----
        if (n0 + r < N && k0 + 32 <= K) {
            *(uint4*)&Bh[r * 40 + c8] = *(const uint4*)&BTh[(size_t)(n0 + r) * K + k0 + c8];
            if (SPLIT)
                *(uint4*)&Bl[r * 40 + c8] = *(const uint4*)&BTl[(size_t)(n0 + r) * K + k0 + c8];
        } else if (n0 + r < N) {
#pragma unroll
            for (int j = 0; j < 8; ++j) {
                int k = k0 + c8 + j;
                Bh[r * 40 + c8 + j] = (k < K) ? BTh[(size_t)(n0 + r) * K + k] : (ushort)0;
                if (SPLIT)
                    Bl[r * 40 + c8 + j] = (k < K) ? BTl[(size_t)(n0 + r) * K + k] : (ushort)0;
            }
        } else {
            uint4 z = {0, 0, 0, 0};
            *(uint4*)&Bh[r * 40 + c8] = z;
            if (SPLIT) *(uint4*)&Bl[r * 40 + c8] = z;
        }
        __syncthreads();

        bf16x8 afh = *(const bf16x8*)&Ah[(wv * 16 + lm) * 40 + lq * 8];
        bf16x8 afl;
        if (SPLIT) afl = *(const bf16x8*)&Al[(wv * 16 + lm) * 40 + lq * 8];
#pragma unroll
        for (int nb = 0; nb < 4; ++nb) {
            bf16x8 bfh = *(const bf16x8*)&Bh[(nb * 16 + lm) * 40 + lq * 8];
            acc[nb] = __builtin_amdgcn_mfma_f32_16x16x32_bf16(afh, bfh, acc[nb], 0, 0, 0);
            if (SPLIT) {
                bf16x8 bfl = *(const bf16x8*)&Bl[(nb * 16 + lm) * 40 + lq * 8];
                acc[nb] = __builtin_amdgcn_mfma_f32_16x16x32_bf16(afl, bfh, acc[nb], 0, 0, 0);
                acc[nb] = __builtin_amdgcn_mfma_f32_16x16x32_bf16(afh, bfl, acc[nb], 0, 0, 0);
            }
        }
    }

    const int row = m0 + wv * 16 + lq * 4;
#pragma unroll
    for (int nb = 0; nb < 4; ++nb) {
        int col = n0 + nb * 16 + lm;
        if (col < N) {
            float bv = bias ? bias[col] : 0.f;
#pragma unroll
            for (int rr = 0; rr < 4; ++rr) {
                float v = acc[nb][rr] + bv;
                if (ACT) v = fmaxf(v, 0.f);
                store_out(&C[(size_t)(row + rr) * N + col], v);
            }
        }
    }
}

// ---------------------------------------------------------------------------
// MFMA MHA: one block per (b, h, q-half). 4 waves; wave handles 16-q tiles.
// K staged row-major (304 x 36 pad), V transposed (32 x 328 pad), bf16-hi.
// Scores: 19 MFMAs (K-dim=32 = 1 step). Softmax in registers (quad shuffles).
// P -> per-wave LDS (16 x 168) in two key-chunks -> A-frags -> P@V MFMAs.
// ---------------------------------------------------------------------------
__global__ __launch_bounds__(256) void mha_mfma_kernel(
    const float* __restrict__ qh, const float* __restrict__ kh,
    const float* __restrict__ vh, float* __restrict__ outp)
{
    __shared__ ushort Kh[304 * 36];      // 21888 B
    __shared__ ushort Vth[32 * 328];     // 20992 B
    __shared__ ushort Pb[4][16 * 168];   // 21504 B   (total 64384 B)

    const int tid = threadIdx.x;
    const int wv = tid >> 6, lane = tid & 63;
    const int bh = blockIdx.x >> 1, half = blockIdx.x & 1;
    const int b = bh >> 3, h = bh & 7;
    const size_t base = (size_t)b * NQL * DM + h * HDIM;

    // stage K rows 0..303 (rows >=300 zero)
    for (int idx = tid; idx < 304 * 32; idx += 256) {
        int row = idx >> 5, d = idx & 31;
        float v = (row < NQL) ? kh[base + (size_t)row * DM + d] : 0.f;
        Kh[row * 36 + d] = f2b(v);
    }
    // stage V transposed, keys 0..327 (keys >=300 zero)
    for (int idx = tid; idx < 328 * 32; idx += 256) {
        int key = idx >> 5, d = idx & 31;
        float v = (key < NQL) ? vh[base + (size_t)key * DM + d] : 0.f;
        Vth[d * 328 + key] = f2b(v);
    }
    // zero own P buffer (cols >= written range must be 0)
    for (int i = lane; i < 16 * 168; i += 64) Pb[wv][i] = 0;
    __syncthreads();

    const int quad = lane >> 4, c = lane & 15;
    const float scale = 0.17677669529663687f;  // 1/sqrt(32)

    const int qt_beg = (half ? 10 : 0) + wv;
    const int qt_end = (half ? 19 : 10);
    for (int qt = qt_beg; qt < qt_end; qt += 4) {
        // ---- Q A-frag straight from global (fp32 -> bf16 hi) ----
        const int q = qt * 16 + c;
        const float* qrow = qh + base + (size_t)q * DM + quad * 8;
        float qv[8];
        *(float4*)&qv[0] = *(const float4*)qrow;
        *(float4*)&qv[4] = *(const float4*)(qrow + 4);
        bf16x8 qf;
#pragma unroll
        for (int j = 0; j < 8; ++j) ((ushort*)&qf)[j] = f2b(qv[j]);

        // ---- scores: 19 key tiles ----
        f32x4 sc[19];
#pragma unroll
        for (int kt = 0; kt < 19; ++kt) {
            bf16x8 kf = *(const bf16x8*)&Kh[(kt * 16 + c) * 36 + quad * 8];
            f32x4 a = {};
            a = __builtin_amdgcn_mfma_f32_16x16x32_bf16(qf, kf, a, 0, 0, 0);
            sc[kt] = a;
        }
        // ---- softmax per row r (q = qt*16 + quad*4 + r) ----
        float inv4[4];
#pragma unroll
        for (int r = 0; r < 4; ++r) {
            float mx = -1e30f;
#pragma unroll
            for (int kt = 0; kt < 19; ++kt) {
                float s = sc[kt][r] * scale;
                if (kt * 16 + c >= NQL) s = -1e30f;
                sc[kt][r] = s;
                mx = fmaxf(mx, s);
            }
#pragma unroll
            for (int m = 1; m < 16; m <<= 1) mx = fmaxf(mx, __shfl_xor(mx, m, 64));
            float l = 0.f;
#pragma unroll
            for (int kt = 0; kt < 19; ++kt) {
                float p = __expf(sc[kt][r] - mx);
                sc[kt][r] = p;
                l += p;
            }
#pragma unroll
            for (int m = 1; m < 16; m <<= 1) l += __shfl_xor(l, m, 64);
            inv4[r] = 1.f / l;
        }

        // ---- P@V in two key-chunks through per-wave LDS ----
        f32x4 o0 = {}, o1 = {};
        // chunk A: key tiles 0..9 (keys 0..159)
#pragma unroll
        for (int r = 0; r < 4; ++r)
#pragma unroll
            for (int kt = 0; kt < 10; ++kt)
                Pb[wv][(quad * 4 + r) * 168 + kt * 16 + c] = f2b(sc[kt][r] * inv4[r]);
#pragma unroll
        for (int ks = 0; ks < 5; ++ks) {
            bf16x8 pf = *(const bf16x8*)&Pb[wv][c * 168 + ks * 32 + quad * 8];
            bf16x8 v0 = *(const bf16x8*)&Vth[c * 328 + ks * 32 + quad * 8];
            bf16x8 v1 = *(const bf16x8*)&Vth[(16 + c) * 328 + ks * 32 + quad * 8];
            o0 = __builtin_amdgcn_mfma_f32_16x16x32_bf16(pf, v0, o0, 0, 0, 0);
            o1 = __builtin_amdgcn_mfma_f32_16x16x32_bf16(pf, v1, o1, 0, 0, 0);
        }
        // chunk B: key tiles 10..18 (keys 160..303), cols 144..159 zeroed
#pragma unroll
        for (int r = 0; r < 4; ++r) {
#pragma unroll
            for (int kt = 10; kt < 19; ++kt)
                Pb[wv][(quad * 4 + r) * 168 + (kt - 10) * 16 + c] = f2b(sc[kt][r] * inv4[r]);
            Pb[wv][(quad * 4 + r) * 168 + 144 + c] = 0;
        }
#pragma unroll
        for (int ks = 0; ks < 5; ++ks) {
            bf16x8 pf = *(const bf16x8*)&Pb[wv][c * 168 + ks * 32 + quad * 8];
            bf16x8 v0 = *(const bf16x8*)&Vth[c * 328 + 160 + ks * 32 + quad * 8];
            bf16x8 v1 = *(const bf16x8*)&Vth[(16 + c) * 328 + 160 + ks * 32 + quad * 8];
            o0 = __builtin_amdgcn_mfma_f32_16x16x32_bf16(pf, v0, o0, 0, 0, 0);
            o1 = __builtin_amdgcn_mfma_f32_16x16x32_bf16(pf, v1, o1, 0, 0, 0);
        }

        // ---- write out: D layout col=c, row=quad*4+r ----
#pragma unroll
        for (int r = 0; r < 4; ++r) {
            const int qq = qt * 16 + quad * 4 + r;
            if (qq < NQL) {
                outp[base + (size_t)qq * DM + c] = o0[r];
                outp[base + (size_t)qq * DM + 16 + c] = o1[r];
            }
        }
    }
}

// ---------------------------------------------------------------------------
// Deformable sampling: one block per (b, q). thread t: h=t>>5, d=t&31.
// ---------------------------------------------------------------------------
__global__ __launch_bounds__(256) void deform_kernel(
    const ushort* __restrict__ val, const float* __restrict__ off,
    const float* __restrict__ awl, const float* __restrict__ refd,
    float* __restrict__ outp)
{
    __shared__ float offs[192];
    __shared__ float aws[96];
    __shared__ float rr[4];
    const int row = blockIdx.x;        // b*NQL + q
    const int b = row / NQL;
    const int t = threadIdx.x;
    if (t < 192) offs[t] = off[(size_t)row * 192 + t];
    if (t < 96)  aws[t] = awl[(size_t)row * 96 + t];
    if (t < 4)   rr[t] = refd[row * 4 + t];
    __syncthreads();

    const int h = t >> 5, d = t & 31;
    float mx = -1e30f;
#pragma unroll
    for (int j = 0; j < 12; ++j) mx = fmaxf(mx, aws[h * 12 + j]);
    float ev[12]; float se = 0.f;
#pragma unroll
    for (int j = 0; j < 12; ++j) { ev[j] = __expf(aws[h * 12 + j] - mx); se += ev[j]; }
    const float inv = 1.f / se;

    const int HWs[3] = {80, 40, 20};
    const int STs[3] = {0, 6400, 8000};
    float acc = 0.f;
#pragma unroll
    for (int l = 0; l < NLVL; ++l) {
        const int Wd = HWs[l], Hd = HWs[l], st = STs[l];
#pragma unroll
        for (int p = 0; p < NPT; ++p) {
            const float w12 = ev[l * 4 + p] * inv;
            const float ox = offs[((h * 3 + l) * 4 + p) * 2 + 0];
            const float oy = offs[((h * 3 + l) * 4 + p) * 2 + 1];
            const float x = (rr[0] + ox * 0.125f * rr[2]) * Wd - 0.5f;
            const float y = (rr[1] + oy * 0.125f * rr[3]) * Hd - 0.5f;
            const float xf = floorf(x), yf = floorf(y);
            const int x0 = (int)xf, y0 = (int)yf;
            const float wx = x - xf, wy = y - yf;
            const float tw[4] = {(1 - wx) * (1 - wy), wx * (1 - wy),
                                 (1 - wx) * wy,       wx * wy};
            const int xs[4] = {x0, x0 + 1, x0, x0 + 1};
            const int ys[4] = {y0, y0, y0 + 1, y0 + 1};
            float sv = 0.f;
#pragma unroll
            for (int tp = 0; tp < 4; ++tp) {
                const int xi = xs[tp], yi = ys[tp];
                if (xi >= 0 && xi < Wd && yi >= 0 && yi < Hd) {
                    const int idx = st + yi * Wd + xi;
                    sv += tw[tp] * b2f(val[((size_t)b * LVTOT + idx) * DM + h * HDIM + d]);
                }
            }
            acc += w12 * sv;
        }
    }
    outp[(size_t)row * DM + t] = acc;
}

// ---------------------------------------------------------------------------
// Fused residual add + LayerNorm (fp32). One wave per row.
// ---------------------------------------------------------------------------
__global__ __launch_bounds__(256) void addln_kernel(
    const float* x, const float* __restrict__ dl,
    const float* __restrict__ g, const float* __restrict__ bb,
    float* outf, const float* __restrict__ qpos, float* __restrict__ q2)
{
    const int wv = threadIdx.x >> 6, lane = threadIdx.x & 63;
    const int row = blockIdx.x * 4 + wv;
    const size_t base = (size_t)row * DM + lane * 4;
    const float4 xv = *(const float4*)(x + base);
    const float4 dv = *(const float4*)(dl + base);
    float v[4] = {xv.x + dv.x, xv.y + dv.y, xv.z + dv.z, xv.w + dv.w};

    float s = v[0] + v[1] + v[2] + v[3];
#pragma unroll
    for (int m = 32; m; m >>= 1) s += __shfl_xor(s, m, 64);
    const float mean = s * (1.f / 256.f);
    float sq = 0.f;
#pragma unroll
    for (int j = 0; j < 4; ++j) { float dd = v[j] - mean; sq += dd * dd; }
#pragma unroll
    for (int m = 32; m; m >>= 1) sq += __shfl_xor(sq, m, 64);
    const float rstd = rsqrtf(sq * (1.f / 256.f) + 1e-5f);

    float y[4];
#pragma unroll
    for (int j = 0; j < 4; ++j) {
        const int col = lane * 4 + j;
        y[j] = (v[j] - mean) * rstd * g[col] + bb[col];
    }
    *(float4*)(outf + base) = make_float4(y[0], y[1], y[2], y[3]);
    if (q2) {
        const float4 qp = *(const float4*)(qpos + base);
        *(float4*)(q2 + base) = make_float4(y[0] + qp.x, y[1] + qp.y,
                                            y[2] + qp.z, y[3] + qp.w);
    }
}

// ---------------------------------------------------------------------------
// Small elementwise kernels
// ---------------------------------------------------------------------------
__global__ __launch_bounds__(256) void init_ref_kernel(
    const float* __restrict__ rpu, float* __restrict__ refd, int n)
{
    int i = blockIdx.x * 256 + threadIdx.x;
    if (i < n) refd[i] = 1.f / (1.f + __expf(-rpu[i]));
}

__global__ __launch_bounds__(256) void prep_kernel(
    const float* __restrict__ outf, const float* __restrict__ qpos,
    float* __restrict__ qf, int n)
{
    int i = blockIdx.x * 256 + threadIdx.x;
    if (i < n) qf[i] = outf[i] + qpos[i];
}

__global__ __launch_bounds__(256) void refupd_kernel(
    const float* __restrict__ b3, float* __restrict__ refd,
    float* __restrict__ dout, int writeout)
{
    int i = blockIdx.x * 256 + threadIdx.x;
    if (i < NROW * 4) {
        float r = fminf(fmaxf(refd[i], 0.f), 1.f);
        float invs = logf(fmaxf(r, 1e-5f)) - logf(fmaxf(1.f - r, 1e-5f));
        float v = 1.f / (1.f + __expf(-(b3[i] + invs)));
        refd[i] = v;
        if (writeout) dout[i] = v;
    }
}

// ---------------------------------------------------------------------------
// Host launch
// ---------------------------------------------------------------------------
extern "C" void kernel_launch(void* const* d_in, const int* in_sizes, int n_in,
                              void* d_out, int out_size, void* d_ws, size_t ws_size,
                              hipStream_t stream)
{
    const float* tgt    = (const float*)d_in[0];
    const float* rpu    = (const float*)d_in[1];
    const float* memory = (const float*)d_in[2];
    const float* Wq  = (const float*)d_in[5];  const float* bq  = (const float*)d_in[6];
    const float* Wk  = (const float*)d_in[7];  const float* bk  = (const float*)d_in[8];
    const float* Wv  = (const float*)d_in[9];  const float* bv  = (const float*)d_in[10];
    const float* Wo  = (const float*)d_in[11]; const float* bo  = (const float*)d_in[12];
    const float* ln1g = (const float*)d_in[13]; const float* ln1b = (const float*)d_in[14];
    const float* ln2g = (const float*)d_in[15]; const float* ln2b = (const float*)d_in[16];
    const float* ln3g = (const float*)d_in[17]; const float* ln3b = (const float*)d_in[18];
    const float* Wvp = (const float*)d_in[19]; const float* bvp = (const float*)d_in[20];
    const float* Woff = (const float*)d_in[21]; const float* boff = (const float*)d_in[22];
    const float* Waw = (const float*)d_in[23]; const float* baw = (const float*)d_in[24];
    const float* Wop = (const float*)d_in[25]; const float* bop = (const float*)d_in[26];
    const float* Wff1 = (const float*)d_in[27]; const float* bff1 = (const float*)d_in[28];
    const float* Wff2 = (const float*)d_in[29]; const float* bff2 = (const float*)d_in[30];
    const float* Wb1 = (const float*)d_in[31]; const float* bb1 = (const float*)d_in[32];
    const float* Wb2 = (const float*)d_in[33]; const float* bb2 = (const float*)d_in[34];
    const float* Wb3 = (const float*)d_in[35]; const float* bb3 = (const float*)d_in[36];
    const float* Ws  = (const float*)d_in[37]; const float* bs_ = (const float*)d_in[38];
    const float* Wp1 = (const float*)d_in[39]; const float* bp1 = (const float*)d_in[40];
    const float* Wp2 = (const float*)d_in[41]; const float* bp2 = (const float*)d_in[42];

    size_t off = 0;
    auto alloc = [&](size_t elems, size_t elsz) -> void* {
        void* r = (char*)d_ws + off;
        off += elems * elsz;
        off = (off + 255) & ~(size_t)255;
        return r;
    };
    ushort *wqh = (ushort*)alloc(6 * 65536, 2), *wql = (ushort*)alloc(6 * 65536, 2);
    ushort *wkh = (ushort*)alloc(6 * 65536, 2), *wkl = (ushort*)alloc(6 * 65536, 2);
    ushort *wvh = (ushort*)alloc(6 * 65536, 2), *wvl = (ushort*)alloc(6 * 65536, 2);
    ushort *woh = (ushort*)alloc(6 * 65536, 2), *wol = (ushort*)alloc(6 * 65536, 2);
    ushort *wvph = (ushort*)alloc(6 * 65536, 2), *wvpl = (ushort*)alloc(6 * 65536, 2);
    ushort *woffh = (ushort*)alloc(6 * 49152, 2), *woffl = (ushort*)alloc(6 * 49152, 2);
    ushort *wawh = (ushort*)alloc(6 * 24576, 2), *wawl2 = (ushort*)alloc(6 * 24576, 2);
    ushort *woph = (ushort*)alloc(6 * 65536, 2), *wopl = (ushort*)alloc(6 * 65536, 2);
    ushort *wf1h = (ushort*)alloc(6 * 262144, 2), *wf1l = (ushort*)alloc(6 * 262144, 2);
    ushort *wf2h = (ushort*)alloc(6 * 262144, 2), *wf2l = (ushort*)alloc(6 * 262144, 2);
    ushort *wb1h = (ushort*)alloc(6 * 65536, 2), *wb1l = (ushort*)alloc(6 * 65536, 2);
    ushort *wb2h = (ushort*)alloc(6 * 65536, 2), *wb2l = (ushort*)alloc(6 * 65536, 2);
    ushort *wb3h = (ushort*)alloc(6 * 1024, 2), *wb3l = (ushort*)alloc(6 * 1024, 2);
    ushort *wsh = (ushort*)alloc(6 * 20480, 2), *wsl = (ushort*)alloc(6 * 20480, 2);
    ushort *wp1h = (ushort*)alloc(2048, 2), *wp1l = (ushort*)alloc(2048, 2);
    ushort *wp2h = (ushort*)alloc(131072, 2), *wp2l = (ushort*)alloc(131072, 2);

    ushort* val_bf = (ushort*)alloc((size_t)BSZ * LVTOT * DM, 2);   // 68.8 MB
    float*  out_f  = (float*)alloc(NROW * DM, 4);
    float*  qpos_f = (float*)alloc(NROW * DM, 4);
    float*  q_f    = (float*)alloc(NROW * DM, 4);
    float*  q2_f   = (float*)alloc(NROW * DM, 4);
    float*  tmp_f  = (float*)alloc(NROW * DM, 4);
    float*  b3_f   = (float*)alloc(NROW * 4, 4);
    float*  refd_f = (float*)alloc(NROW * 4, 4);
    float* arena = (float*)alloc(NROW * 1024, 4);   // 19.7 MB, phase-disjoint
    float* t1_f  = arena;
    float* qh_f  = arena;
    float* kh_f  = arena + NROW * DM;
    float* vh_f  = arena + 2 * NROW * DM;
    float* att_f = arena + 3 * NROW * DM;
    float* off_f = arena;
    float* aw_f  = arena + NROW * 192;
    float* samp_f= arena + NROW * 288;
    float* ff_f  = arena;
    float* h1_f  = arena;
    float* h2_f  = arena + NROW * DM;

    if (off > ws_size) return;

    dim3 tb(32, 8);
    auto T = [&](const float* s, ushort* dh, ushort* dl, int K, int N, int B) {
        dim3 g((N + 31) / 32, (K + 31) / 32, B);
        transpose_split_kernel<<<g, tb, 0, stream>>>(s, dh, dl, K, N);
    };
    T(Wq, wqh, wql, 256, 256, 6);   T(Wk, wkh, wkl, 256, 256, 6);
    T(Wv, wvh, wvl, 256, 256, 6);   T(Wo, woh, wol, 256, 256, 6);
    T(Wvp, wvph, wvpl, 256, 256, 6); T(Woff, woffh, woffl, 256, 192, 6);
    T(Waw, wawh, wawl2, 256, 96, 6); T(Wop, woph, wopl, 256, 256, 6);
    T(Wff1, wf1h, wf1l, 256, 1024, 6); T(Wff2, wf2h, wf2l, 1024, 256, 6);
    T(Wb1, wb1h, wb1l, 256, 256, 6); T(Wb2, wb2h, wb2l, 256, 256, 6);
    T(Wb3, wb3h, wb3l, 256, 4, 6);  T(Ws, wsh, wsl, 256, 80, 6);
    T(Wp1, wp1h, wp1l, 4, 512, 1);  T(Wp2, wp2h, wp2l, 512, 256, 1);

    hipMemcpyAsync(out_f, tgt, (size_t)NROW * DM * 4, hipMemcpyDeviceToDevice, stream);
    init_ref_kernel<<<75, 256, 0, stream>>>(rpu, refd_f, NROW * 4);

    auto G = [&](const float* A, const ushort* BTh, const ushort* BTl,
                 const float* bias, float* C, int M, int N, int K, bool relu) {
        dim3 g(M / 64, (N + 63) / 64);
        if (relu) gemm_sp<1, 1, float><<<g, 256, 0, stream>>>(A, BTh, BTl, bias, C, M, N, K);
        else      gemm_sp<0, 1, float><<<g, 256, 0, stream>>>(A, BTh, BTl, bias, C, M, N, K);
    };

    for (int i = 0; i < NLAYERS; ++i) {
        // qpos = relu(ref_d @ Wp1 + bp1) @ Wp2 + bp2
        G(refd_f, wp1h, wp1l, bp1, t1_f, NROW, 512, 4, true);
        G(t1_f, wp2h, wp2l, bp2, qpos_f, NROW, 256, 512, false);
        prep_kernel<<<4800, 256, 0, stream>>>(out_f, qpos_f, q_f, NROW * DM);
        // MHA
        G(q_f, wqh + i * 65536, wql + i * 65536, bq + i * 256, qh_f, NROW, 256, 256, false);
        G(q_f, wkh + i * 65536, wkl + i * 65536, bk + i * 256, kh_f, NROW, 256, 256, false);
        G(out_f, wvh + i * 65536, wvl + i * 65536, bv + i * 256, vh_f, NROW, 256, 256, false);
        mha_mfma_kernel<<<256, 256, 0, stream>>>(qh_f, kh_f, vh_f, att_f);
        G(att_f, woh + i * 65536, wol + i * 65536, bo + i * 256, tmp_f, NROW, 256, 256, false);
        addln_kernel<<<1200, 256, 0, stream>>>(out_f, tmp_f, ln1g + i * 256, ln1b + i * 256,
                                               out_f, qpos_f, q2_f);
        // Deformable attention (val-proj: bf16-grade, single-plane)
        {
            dim3 g((BSZ * LVTOT) / 64, 4);
            gemm_sp<0, 0, ushort><<<g, 256, 0, stream>>>(
                memory, wvph + i * 65536, wvpl + i * 65536, bvp + i * 256,
                val_bf, BSZ * LVTOT, 256, 256);
        }
        G(q2_f, woffh + i * 49152, woffl + i * 49152, boff + i * 192, off_f, NROW, 192, 256, false);
        G(q2_f, wawh + i * 24576, wawl2 + i * 24576, baw + i * 96, aw_f, NROW, 96, 256, false);
        deform_kernel<<<4800, 256, 0, stream>>>(val_bf, off_f, aw_f, refd_f, samp_f);
        G(samp_f, woph + i * 65536, wopl + i * 65536, bop + i * 256, tmp_f, NROW, 256, 256, false);
        addln_kernel<<<1200, 256, 0, stream>>>(out_f, tmp_f, ln2g + i * 256, ln2b + i * 256,
                                               out_f, nullptr, nullptr);
        // FFN
        G(out_f, wf1h + i * 262144, wf1l + i * 262144, bff1 + i * 1024, ff_f, NROW, 1024, 256, true);
        G(ff_f, wf2h + i * 262144, wf2l + i * 262144, bff2 + i * 256, tmp_f, NROW, 256, 1024, false);
        addln_kernel<<<1200, 256, 0, stream>>>(out_f, tmp_f, ln3g + i * 256, ln3b + i * 256,
                                               out_f, nullptr, nullptr);
        // bbox head
        G(out_f, wb1h + i * 65536, wb1l + i * 65536, bb1 + i * 256, h1_f, NROW, 256, 256, true);
        G(h1_f, wb2h + i * 65536, wb2l + i * 65536, bb2 + i * 256, h2_f, NROW, 256, 256, true);
        G(h2_f, wb3h + i * 1024, wb3l + i * 1024, bb3 + i * 4, b3_f, NROW, 4, 256, false);
        refupd_kernel<<<75, 256, 0, stream>>>(b3_f, refd_f, (float*)d_out,
                                              (i == NLAYERS - 1) ? 1 : 0);
        if (i == NLAYERS - 1) {
            G(out_f, wsh + i * 20480, wsl + i * 20480, bs_ + i * 80,
              (float*)d_out + NROW * 4, NROW, 80, 256, false);
        }
    }
}

// Round 5
// 2484.629 us; speedup vs baseline: 1.7779x; 1.1307x over previous
//
#include <hip/hip_runtime.h>

#define NLAYERS 6
#define BSZ 16
#define NQL 300
#define DM 256
#define NHEAD 8
#define HDIM 32
#define NLVL 3
#define NPT 4
#define DFFN 1024
#define NCLS 80
#define LVTOT 8400
#define NROW (BSZ * NQL)   // 4800

typedef __attribute__((ext_vector_type(8))) short bf16x8;
typedef __attribute__((ext_vector_type(8))) ushort us8;
typedef __attribute__((ext_vector_type(4))) float f32x4;

__device__ __forceinline__ float b2f(ushort u) {
    return __uint_as_float(((uint)u) << 16);
}
__device__ __forceinline__ ushort f2b(float f) {
    uint i = __float_as_uint(f);
    uint r = i + 0x7fffu + ((i >> 16) & 1u);   // RNE
    return (ushort)(r >> 16);
}
__device__ __forceinline__ void split2(float v, ushort& h, ushort& l) {
    ushort hh = f2b(v);
    h = hh;
    l = f2b(v - b2f(hh));
}
__device__ __forceinline__ void store_out(float* p, float v) { *p = v; }
__device__ __forceinline__ void store_out(ushort* p, float v) { *p = f2b(v); }

// ---------------------------------------------------------------------------
// Batched transpose + bf16 hi/lo split: src fp32 (B,K,N) -> dst (B, drow0+N, K)
// dst layer stride = dlstride elements; rows [drow0, drow0+N) within layer.
// ---------------------------------------------------------------------------
__global__ __launch_bounds__(256) void transpose_split_kernel(
    const float* __restrict__ src, ushort* __restrict__ dh,
    ushort* __restrict__ dl, int K, int N, int dlstride, int drow0)
{
    __shared__ float tile[32][33];
    src += (size_t)blockIdx.z * (size_t)K * (size_t)N;
    const size_t doff = (size_t)blockIdx.z * dlstride + (size_t)drow0 * K;
    dh += doff; dl += doff;
    const int n0 = blockIdx.x * 32, k0 = blockIdx.y * 32;
    const int tx = threadIdx.x, ty = threadIdx.y;   // 32 x 8
    for (int r = 0; r < 32; r += 8) {
        int k = k0 + ty + r, n = n0 + tx;
        if (k < K && n < N) tile[ty + r][tx] = src[(size_t)k * N + n];
    }
    __syncthreads();
    for (int r = 0; r < 32; r += 8) {
        int n = n0 + ty + r, k = k0 + tx;
        if (n < N && k < K) {
            ushort h, l;
            split2(tile[tx][ty + r], h, l);
            dh[(size_t)n * K + k] = h;
            dl[(size_t)n * K + k] = l;
        }
    }
}

// ---------------------------------------------------------------------------
// Bias concat: dst[l*(na+nb) + j] = j<na ? a[l*na+j] : b[l*nb+j-na],  l<nl
// ---------------------------------------------------------------------------
__global__ __launch_bounds__(256) void concat2_kernel(
    const float* __restrict__ a, int na, const float* __restrict__ b, int nb,
    float* __restrict__ dst, int nl)
{
    const int tot = na + nb;
    int i = blockIdx.x * 256 + threadIdx.x;
    if (i < nl * tot) {
        int l = i / tot, j = i - l * tot;
        dst[i] = (j < na) ? a[l * na + j] : b[l * nb + j - na];
    }
}

// ---------------------------------------------------------------------------
// Split-bf16 MFMA GEMM (64x64 tile): C = act(A@B + bias), A fp32,
// B transposed pre-split planes. D = Ah*Bh + Al*Bh + Ah*Bl.
// ---------------------------------------------------------------------------
template <int ACT, typename TOUT>
__global__ __launch_bounds__(256) void gemm_sp(
    const float* __restrict__ A, const ushort* __restrict__ BTh,
    const ushort* __restrict__ BTl, const float* __restrict__ bias,
    TOUT* __restrict__ C, int M, int N, int K)
{
    __shared__ ushort Ah[64 * 40];
    __shared__ ushort Al[64 * 40];
    __shared__ ushort Bh[64 * 40];
    __shared__ ushort Bl[64 * 40];

    const int tid  = threadIdx.x;
    const int m0   = blockIdx.x * 64;
    const int n0   = blockIdx.y * 64;
    const int wv   = tid >> 6;
    const int lane = tid & 63;
    const int lm   = lane & 15;
    const int lq   = lane >> 4;
    const int r    = tid >> 2;
    const int c8   = (tid & 3) * 8;

    f32x4 acc[4] = {};

    for (int k0 = 0; k0 < K; k0 += 32) {
        __syncthreads();
        {
            float av[8];
            if (k0 + 32 <= K) {
                *(float4*)&av[0] = *(const float4*)&A[(size_t)(m0 + r) * K + k0 + c8];
                *(float4*)&av[4] = *(const float4*)&A[(size_t)(m0 + r) * K + k0 + c8 + 4];
            } else {
#pragma unroll
                for (int j = 0; j < 8; ++j) {
                    int k = k0 + c8 + j;
                    av[j] = (k < K) ? A[(size_t)(m0 + r) * K + k] : 0.f;
                }
            }
            us8 hv, lv;
#pragma unroll
            for (int j = 0; j < 8; ++j) {
                ushort h, l;
                split2(av[j], h, l);
                hv[j] = h; lv[j] = l;
            }
            *(us8*)&Ah[r * 40 + c8] = hv;
            *(us8*)&Al[r * 40 + c8] = lv;
        }
        if (n0 + r < N && k0 + 32 <= K) {
            *(uint4*)&Bh[r * 40 + c8] = *(const uint4*)&BTh[(size_t)(n0 + r) * K + k0 + c8];
            *(uint4*)&Bl[r * 40 + c8] = *(const uint4*)&BTl[(size_t)(n0 + r) * K + k0 + c8];
        } else if (n0 + r < N) {
#pragma unroll
            for (int j = 0; j < 8; ++j) {
                int k = k0 + c8 + j;
                Bh[r * 40 + c8 + j] = (k < K) ? BTh[(size_t)(n0 + r) * K + k] : (ushort)0;
                Bl[r * 40 + c8 + j] = (k < K) ? BTl[(size_t)(n0 + r) * K + k] : (ushort)0;
            }
        } else {
            uint4 z = {0, 0, 0, 0};
            *(uint4*)&Bh[r * 40 + c8] = z;
            *(uint4*)&Bl[r * 40 + c8] = z;
        }
        __syncthreads();

        bf16x8 afh = *(const bf16x8*)&Ah[(wv * 16 + lm) * 40 + lq * 8];
        bf16x8 afl = *(const bf16x8*)&Al[(wv * 16 + lm) * 40 + lq * 8];
#pragma unroll
        for (int nb = 0; nb < 4; ++nb) {
            bf16x8 bfh = *(const bf16x8*)&Bh[(nb * 16 + lm) * 40 + lq * 8];
            bf16x8 bfl = *(const bf16x8*)&Bl[(nb * 16 + lm) * 40 + lq * 8];
            acc[nb] = __builtin_amdgcn_mfma_f32_16x16x32_bf16(afh, bfh, acc[nb], 0, 0, 0);
            acc[nb] = __builtin_amdgcn_mfma_f32_16x16x32_bf16(afl, bfh, acc[nb], 0, 0, 0);
            acc[nb] = __builtin_amdgcn_mfma_f32_16x16x32_bf16(afh, bfl, acc[nb], 0, 0, 0);
        }
    }

    const int row = m0 + wv * 16 + lq * 4;
#pragma unroll
    for (int nb = 0; nb < 4; ++nb) {
        int col = n0 + nb * 16 + lm;
        if (col < N) {
            float bv = bias ? bias[col] : 0.f;
#pragma unroll
            for (int rr = 0; rr < 4; ++rr) {
                float v = acc[nb][rr] + bv;
                if (ACT) v = fmaxf(v, 0.f);
                store_out(&C[(size_t)(row + rr) * N + col], v);
            }
        }
    }
}

// ---------------------------------------------------------------------------
// Fat-tile bf16-grade GEMM (128x128, 4 waves, 4x4 acc/wave): C bf16 =
// A(fp32, hi-rounded) @ B(bf16-hi, transposed) + bias.  M%128==0, N%128==0,
// K%32==0. Grid: (N/128, M/128) — N on x so A-tile sharers are adjacent (L2).
// ---------------------------------------------------------------------------
__global__ __launch_bounds__(256) void gemm_big(
    const float* __restrict__ A, const ushort* __restrict__ BTh,
    const float* __restrict__ bias, ushort* __restrict__ C,
    int M, int N, int K)
{
    __shared__ ushort As[128 * 32];
    __shared__ ushort Bs[128 * 32];
    const int tid = threadIdx.x;
    const int n0 = blockIdx.x * 128, m0 = blockIdx.y * 128;
    const int wv = tid >> 6, lane = tid & 63;
    const int lm = lane & 15, quad = lane >> 4;
    const int wr = wv >> 1, wc = wv & 1;
    const int r = tid >> 2, c8 = (tid & 3) * 8;

    f32x4 acc[4][4] = {};

    for (int k0 = 0; k0 < K; k0 += 32) {
        __syncthreads();
#pragma unroll
        for (int hf = 0; hf < 2; ++hf) {
            const float* ga = &A[(size_t)(m0 + hf * 64 + r) * K + k0 + c8];
            float av[8];
            *(float4*)&av[0] = *(const float4*)ga;
            *(float4*)&av[4] = *(const float4*)(ga + 4);
            us8 hv;
#pragma unroll
            for (int j = 0; j < 8; ++j) hv[j] = f2b(av[j]);
            *(us8*)&As[(hf * 64 + r) * 32 + c8] = hv;
            *(uint4*)&Bs[(hf * 64 + r) * 32 + c8] =
                *(const uint4*)&BTh[(size_t)(n0 + hf * 64 + r) * K + k0 + c8];
        }
        __syncthreads();

        bf16x8 af[4], bfr[4];
#pragma unroll
        for (int i = 0; i < 4; ++i)
            af[i] = *(const bf16x8*)&As[(wr * 64 + i * 16 + lm) * 32 + quad * 8];
#pragma unroll
        for (int i = 0; i < 4; ++i)
            bfr[i] = *(const bf16x8*)&Bs[(wc * 64 + i * 16 + lm) * 32 + quad * 8];
#pragma unroll
        for (int mi = 0; mi < 4; ++mi)
#pragma unroll
            for (int ni = 0; ni < 4; ++ni)
                acc[mi][ni] = __builtin_amdgcn_mfma_f32_16x16x32_bf16(
                    af[mi], bfr[ni], acc[mi][ni], 0, 0, 0);
    }

#pragma unroll
    for (int ni = 0; ni < 4; ++ni) {
        const int col = n0 + wc * 64 + ni * 16 + lm;
        const float bv = bias[col];
#pragma unroll
        for (int mi = 0; mi < 4; ++mi) {
            const int row = m0 + wr * 64 + mi * 16 + quad * 4;
#pragma unroll
            for (int rr = 0; rr < 4; ++rr)
                C[(size_t)(row + rr) * N + col] = f2b(acc[mi][ni][rr] + bv);
        }
    }
}

// ---------------------------------------------------------------------------
// MFMA MHA: one block per (b, h, q-half). q/k/v have row strides ldq/ldk/ldv.
// ---------------------------------------------------------------------------
__global__ __launch_bounds__(256) void mha_mfma_kernel(
    const float* __restrict__ qh, int ldq, const float* __restrict__ kh, int ldk,
    const float* __restrict__ vh, int ldv, float* __restrict__ outp)
{
    __shared__ ushort Kh[304 * 36];
    __shared__ ushort Vth[32 * 328];
    __shared__ ushort Pb[4][16 * 168];

    const int tid = threadIdx.x;
    const int wv = tid >> 6, lane = tid & 63;
    const int bh = blockIdx.x >> 1, half = blockIdx.x & 1;
    const int b = bh >> 3, h = bh & 7;
    const size_t qbase = (size_t)b * NQL * ldq + h * HDIM;
    const size_t kbase = (size_t)b * NQL * ldk + h * HDIM;
    const size_t vbase = (size_t)b * NQL * ldv + h * HDIM;
    const size_t obase = (size_t)b * NQL * DM + h * HDIM;

    for (int idx = tid; idx < 304 * 32; idx += 256) {
        int row = idx >> 5, d = idx & 31;
        float v = (row < NQL) ? kh[kbase + (size_t)row * ldk + d] : 0.f;
        Kh[row * 36 + d] = f2b(v);
    }
    for (int idx = tid; idx < 328 * 32; idx += 256) {
        int key = idx >> 5, d = idx & 31;
        float v = (key < NQL) ? vh[vbase + (size_t)key * ldv + d] : 0.f;
        Vth[d * 328 + key] = f2b(v);
    }
    for (int i = lane; i < 16 * 168; i += 64) Pb[wv][i] = 0;
    __syncthreads();

    const int quad = lane >> 4, c = lane & 15;
    const float scale = 0.17677669529663687f;

    const int qt_beg = (half ? 10 : 0) + wv;
    const int qt_end = (half ? 19 : 10);
    for (int qt = qt_beg; qt < qt_end; qt += 4) {
        const int q = qt * 16 + c;
        const float* qrow = qh + qbase + (size_t)q * ldq + quad * 8;
        float qv[8];
        *(float4*)&qv[0] = *(const float4*)qrow;
        *(float4*)&qv[4] = *(const float4*)(qrow + 4);
        bf16x8 qf;
#pragma unroll
        for (int j = 0; j < 8; ++j) ((ushort*)&qf)[j] = f2b(qv[j]);

        f32x4 sc[19];
#pragma unroll
        for (int kt = 0; kt < 19; ++kt) {
            bf16x8 kf = *(const bf16x8*)&Kh[(kt * 16 + c) * 36 + quad * 8];
            f32x4 a = {};
            a = __builtin_amdgcn_mfma_f32_16x16x32_bf16(qf, kf, a, 0, 0, 0);
            sc[kt] = a;
        }
        float inv4[4];
#pragma unroll
        for (int r = 0; r < 4; ++r) {
            float mx = -1e30f;
#pragma unroll
            for (int kt = 0; kt < 19; ++kt) {
                float s = sc[kt][r] * scale;
                if (kt * 16 + c >= NQL) s = -1e30f;
                sc[kt][r] = s;
                mx = fmaxf(mx, s);
            }
#pragma unroll
            for (int m = 1; m < 16; m <<= 1) mx = fmaxf(mx, __shfl_xor(mx, m, 64));
            float l = 0.f;
#pragma unroll
            for (int kt = 0; kt < 19; ++kt) {
                float p = __expf(sc[kt][r] - mx);
                sc[kt][r] = p;
                l += p;
            }
#pragma unroll
            for (int m = 1; m < 16; m <<= 1) l += __shfl_xor(l, m, 64);
            inv4[r] = 1.f / l;
        }

        f32x4 o0 = {}, o1 = {};
#pragma unroll
        for (int r = 0; r < 4; ++r)
#pragma unroll
            for (int kt = 0; kt < 10; ++kt)
                Pb[wv][(quad * 4 + r) * 168 + kt * 16 + c] = f2b(sc[kt][r] * inv4[r]);
#pragma unroll
        for (int ks = 0; ks < 5; ++ks) {
            bf16x8 pf = *(const bf16x8*)&Pb[wv][c * 168 + ks * 32 + quad * 8];
            bf16x8 v0 = *(const bf16x8*)&Vth[c * 328 + ks * 32 + quad * 8];
            bf16x8 v1 = *(const bf16x8*)&Vth[(16 + c) * 328 + ks * 32 + quad * 8];
            o0 = __builtin_amdgcn_mfma_f32_16x16x32_bf16(pf, v0, o0, 0, 0, 0);
            o1 = __builtin_amdgcn_mfma_f32_16x16x32_bf16(pf, v1, o1, 0, 0, 0);
        }
#pragma unroll
        for (int r = 0; r < 4; ++r) {
#pragma unroll
            for (int kt = 10; kt < 19; ++kt)
                Pb[wv][(quad * 4 + r) * 168 + (kt - 10) * 16 + c] = f2b(sc[kt][r] * inv4[r]);
            Pb[wv][(quad * 4 + r) * 168 + 144 + c] = 0;
        }
#pragma unroll
        for (int ks = 0; ks < 5; ++ks) {
            bf16x8 pf = *(const bf16x8*)&Pb[wv][c * 168 + ks * 32 + quad * 8];
            bf16x8 v0 = *(const bf16x8*)&Vth[c * 328 + 160 + ks * 32 + quad * 8];
            bf16x8 v1 = *(const bf16x8*)&Vth[(16 + c) * 328 + 160 + ks * 32 + quad * 8];
            o0 = __builtin_amdgcn_mfma_f32_16x16x32_bf16(pf, v0, o0, 0, 0, 0);
            o1 = __builtin_amdgcn_mfma_f32_16x16x32_bf16(pf, v1, o1, 0, 0, 0);
        }
#pragma unroll
        for (int r = 0; r < 4; ++r) {
            const int qq = qt * 16 + quad * 4 + r;
            if (qq < NQL) {
                outp[obase + (size_t)qq * DM + c] = o0[r];
                outp[obase + (size_t)qq * DM + 16 + c] = o1[r];
            }
        }
    }
}

// ---------------------------------------------------------------------------
// Deformable sampling. offaw: per row 288 = 192 offsets + 96 aw logits.
// ---------------------------------------------------------------------------
__global__ __launch_bounds__(256) void deform_kernel(
    const ushort* __restrict__ val, const float* __restrict__ offaw,
    const float* __restrict__ refd, float* __restrict__ outp)
{
    __shared__ float offs[192];
    __shared__ float aws[96];
    __shared__ float rr[4];
    const int row = blockIdx.x;
    const int b = row / NQL;
    const int t = threadIdx.x;
    if (t < 192) offs[t] = offaw[(size_t)row * 288 + t];
    if (t < 96)  aws[t] = offaw[(size_t)row * 288 + 192 + t];
    if (t < 4)   rr[t] = refd[row * 4 + t];
    __syncthreads();

    const int h = t >> 5, d = t & 31;
    float mx = -1e30f;
#pragma unroll
    for (int j = 0; j < 12; ++j) mx = fmaxf(mx, aws[h * 12 + j]);
    float ev[12]; float se = 0.f;
#pragma unroll
    for (int j = 0; j < 12; ++j) { ev[j] = __expf(aws[h * 12 + j] - mx); se += ev[j]; }
    const float inv = 1.f / se;

    const int HWs[3] = {80, 40, 20};
    const int STs[3] = {0, 6400, 8000};
    float acc = 0.f;
#pragma unroll
    for (int l = 0; l < NLVL; ++l) {
        const int Wd = HWs[l], Hd = HWs[l], st = STs[l];
#pragma unroll
        for (int p = 0; p < NPT; ++p) {
            const float w12 = ev[l * 4 + p] * inv;
            const float ox = offs[((h * 3 + l) * 4 + p) * 2 + 0];
            const float oy = offs[((h * 3 + l) * 4 + p) * 2 + 1];
            const float x = (rr[0] + ox * 0.125f * rr[2]) * Wd - 0.5f;
            const float y = (rr[1] + oy * 0.125f * rr[3]) * Hd - 0.5f;
            const float xf = floorf(x), yf = floorf(y);
            const int x0 = (int)xf, y0 = (int)yf;
            const float wx = x - xf, wy = y - yf;
            const float tw[4] = {(1 - wx) * (1 - wy), wx * (1 - wy),
                                 (1 - wx) * wy,       wx * wy};
            const int xs[4] = {x0, x0 + 1, x0, x0 + 1};
            const int ys[4] = {y0, y0, y0 + 1, y0 + 1};
            float sv = 0.f;
#pragma unroll
            for (int tp = 0; tp < 4; ++tp) {
                const int xi = xs[tp], yi = ys[tp];
                if (xi >= 0 && xi < Wd && yi >= 0 && yi < Hd) {
                    const int idx = st + yi * Wd + xi;
                    sv += tw[tp] * b2f(val[((size_t)b * LVTOT + idx) * DM + h * HDIM + d]);
                }
            }
            acc += w12 * sv;
        }
    }
    outp[(size_t)row * DM + t] = acc;
}

// ---------------------------------------------------------------------------
// Fused residual add + LayerNorm (fp32). One wave per row.
// ---------------------------------------------------------------------------
__global__ __launch_bounds__(256) void addln_kernel(
    const float* x, const float* __restrict__ dl,
    const float* __restrict__ g, const float* __restrict__ bb,
    float* outf, const float* __restrict__ qpos, float* __restrict__ q2)
{
    const int wv = threadIdx.x >> 6, lane = threadIdx.x & 63;
    const int row = blockIdx.x * 4 + wv;
    const size_t base = (size_t)row * DM + lane * 4;
    const float4 xv = *(const float4*)(x + base);
    const float4 dv = *(const float4*)(dl + base);
    float v[4] = {xv.x + dv.x, xv.y + dv.y, xv.z + dv.z, xv.w + dv.w};

    float s = v[0] + v[1] + v[2] + v[3];
#pragma unroll
    for (int m = 32; m; m >>= 1) s += __shfl_xor(s, m, 64);
    const float mean = s * (1.f / 256.f);
    float sq = 0.f;
#pragma unroll
    for (int j = 0; j < 4; ++j) { float dd = v[j] - mean; sq += dd * dd; }
#pragma unroll
    for (int m = 32; m; m >>= 1) sq += __shfl_xor(sq, m, 64);
    const float rstd = rsqrtf(sq * (1.f / 256.f) + 1e-5f);

    float y[4];
#pragma unroll
    for (int j = 0; j < 4; ++j) {
        const int col = lane * 4 + j;
        y[j] = (v[j] - mean) * rstd * g[col] + bb[col];
    }
    *(float4*)(outf + base) = make_float4(y[0], y[1], y[2], y[3]);
    if (q2) {
        const float4 qp = *(const float4*)(qpos + base);
        *(float4*)(q2 + base) = make_float4(y[0] + qp.x, y[1] + qp.y,
                                            y[2] + qp.z, y[3] + qp.w);
    }
}

// ---------------------------------------------------------------------------
// Small elementwise kernels
// ---------------------------------------------------------------------------
__global__ __launch_bounds__(256) void init_ref_kernel(
    const float* __restrict__ rpu, float* __restrict__ refd, int n)
{
    int i = blockIdx.x * 256 + threadIdx.x;
    if (i < n) refd[i] = 1.f / (1.f + __expf(-rpu[i]));
}

__global__ __launch_bounds__(256) void prep_kernel(
    const float* __restrict__ outf, const float* __restrict__ qpos,
    float* __restrict__ qf, int n)
{
    int i = blockIdx.x * 256 + threadIdx.x;
    if (i < n) qf[i] = outf[i] + qpos[i];
}

__global__ __launch_bounds__(256) void refupd_kernel(
    const float* __restrict__ b3, float* __restrict__ refd,
    float* __restrict__ dout, int writeout)
{
    int i = blockIdx.x * 256 + threadIdx.x;
    if (i < NROW * 4) {
        float r = fminf(fmaxf(refd[i], 0.f), 1.f);
        float invs = logf(fmaxf(r, 1e-5f)) - logf(fmaxf(1.f - r, 1e-5f));
        float v = 1.f / (1.f + __expf(-(b3[i] + invs)));
        refd[i] = v;
        if (writeout) dout[i] = v;
    }
}

// ---------------------------------------------------------------------------
// Host launch
// ---------------------------------------------------------------------------
extern "C" void kernel_launch(void* const* d_in, const int* in_sizes, int n_in,
                              void* d_out, int out_size, void* d_ws, size_t ws_size,
                              hipStream_t stream)
{
    const float* tgt    = (const float*)d_in[0];
    const float* rpu    = (const float*)d_in[1];
    const float* memory = (const float*)d_in[2];
    const float* Wq  = (const float*)d_in[5];  const float* bq  = (const float*)d_in[6];
    const float* Wk  = (const float*)d_in[7];  const float* bk  = (const float*)d_in[8];
    const float* Wv  = (const float*)d_in[9];  const float* bv  = (const float*)d_in[10];
    const float* Wo  = (const float*)d_in[11]; const float* bo  = (const float*)d_in[12];
    const float* ln1g = (const float*)d_in[13]; const float* ln1b = (const float*)d_in[14];
    const float* ln2g = (const float*)d_in[15]; const float* ln2b = (const float*)d_in[16];
    const float* ln3g = (const float*)d_in[17]; const float* ln3b = (const float*)d_in[18];
    const float* Wvp = (const float*)d_in[19]; const float* bvp = (const float*)d_in[20];
    const float* Woff = (const float*)d_in[21]; const float* boff = (const float*)d_in[22];
    const float* Waw = (const float*)d_in[23]; const float* baw = (const float*)d_in[24];
    const float* Wop = (const float*)d_in[25]; const float* bop = (const float*)d_in[26];
    const float* Wff1 = (const float*)d_in[27]; const float* bff1 = (const float*)d_in[28];
    const float* Wff2 = (const float*)d_in[29]; const float* bff2 = (const float*)d_in[30];
    const float* Wb1 = (const float*)d_in[31]; const float* bb1 = (const float*)d_in[32];
    const float* Wb2 = (const float*)d_in[33]; const float* bb2 = (const float*)d_in[34];
    const float* Wb3 = (const float*)d_in[35]; const float* bb3 = (const float*)d_in[36];
    const float* Ws  = (const float*)d_in[37]; const float* bs_ = (const float*)d_in[38];
    const float* Wp1 = (const float*)d_in[39]; const float* bp1 = (const float*)d_in[40];
    const float* Wp2 = (const float*)d_in[41]; const float* bp2 = (const float*)d_in[42];

    size_t off = 0;
    auto alloc = [&](size_t elems, size_t elsz) -> void* {
        void* r = (char*)d_ws + off;
        off += elems * elsz;
        off = (off + 255) & ~(size_t)255;
        return r;
    };
    // fused Q|K planes: 6 x 512 x 256
    ushort *wqkh = (ushort*)alloc(6 * 131072, 2), *wqkl = (ushort*)alloc(6 * 131072, 2);
    ushort *wvh = (ushort*)alloc(6 * 65536, 2), *wvl = (ushort*)alloc(6 * 65536, 2);
    ushort *woh = (ushort*)alloc(6 * 65536, 2), *wol = (ushort*)alloc(6 * 65536, 2);
    ushort *wvph = (ushort*)alloc(6 * 65536, 2), *wvpl = (ushort*)alloc(6 * 65536, 2);
    // fused off|aw planes: 6 x 320 x 256 (rows 288..319 unused)
    ushort *wfah = (ushort*)alloc(6 * 81920, 2), *wfal = (ushort*)alloc(6 * 81920, 2);
    ushort *woph = (ushort*)alloc(6 * 65536, 2), *wopl = (ushort*)alloc(6 * 65536, 2);
    ushort *wf1h = (ushort*)alloc(6 * 262144, 2), *wf1l = (ushort*)alloc(6 * 262144, 2);
    ushort *wf2h = (ushort*)alloc(6 * 262144, 2), *wf2l = (ushort*)alloc(6 * 262144, 2);
    ushort *wb1h = (ushort*)alloc(6 * 65536, 2), *wb1l = (ushort*)alloc(6 * 65536, 2);
    ushort *wb2h = (ushort*)alloc(6 * 65536, 2), *wb2l = (ushort*)alloc(6 * 65536, 2);
    ushort *wb3h = (ushort*)alloc(6 * 1024, 2), *wb3l = (ushort*)alloc(6 * 1024, 2);
    ushort *wsh = (ushort*)alloc(6 * 20480, 2), *wsl = (ushort*)alloc(6 * 20480, 2);
    ushort *wp1h = (ushort*)alloc(2048, 2), *wp1l = (ushort*)alloc(2048, 2);
    ushort *wp2h = (ushort*)alloc(131072, 2), *wp2l = (ushort*)alloc(131072, 2);
    float  *bqk  = (float*)alloc(6 * 512, 4);
    float  *bfa  = (float*)alloc(6 * 288, 4);

    ushort* val_bf = (ushort*)alloc((size_t)BSZ * LVTOT * DM, 2);   // 68.8 MB
    float*  out_f  = (float*)alloc(NROW * DM, 4);
    float*  qpos_f = (float*)alloc(NROW * DM, 4);
    float*  q_f    = (float*)alloc(NROW * DM, 4);
    float*  q2_f   = (float*)alloc(NROW * DM, 4);
    float*  tmp_f  = (float*)alloc(NROW * DM, 4);
    float*  b3_f   = (float*)alloc(NROW * 4, 4);
    float*  refd_f = (float*)alloc(NROW * 4, 4);
    float* arena = (float*)alloc(NROW * 1024, 4);   // phase-disjoint
    float* t1_f    = arena;                          // 4800 x 512
    float* qk_f    = arena;                          // 4800 x 512
    float* vh_f    = arena + NROW * 512;             // 4800 x 256
    float* att_f   = arena + NROW * 768;             // 4800 x 256
    float* offaw_f = arena;                          // 4800 x 288
    float* samp_f  = arena + NROW * 288;             // 4800 x 256
    float* ff_f    = arena;                          // 4800 x 1024
    float* h1_f    = arena;                          // 4800 x 256
    float* h2_f    = arena + NROW * DM;              // 4800 x 256

    if (off > ws_size) return;

    dim3 tb(32, 8);
    auto T = [&](const float* s, ushort* dh, ushort* dl, int K, int N, int B,
                 int dls, int dr0) {
        dim3 g((N + 31) / 32, (K + 31) / 32, B);
        transpose_split_kernel<<<g, tb, 0, stream>>>(s, dh, dl, K, N, dls, dr0);
    };
    T(Wq, wqkh, wqkl, 256, 256, 6, 131072, 0);
    T(Wk, wqkh, wqkl, 256, 256, 6, 131072, 256);
    T(Wv, wvh, wvl, 256, 256, 6, 65536, 0);
    T(Wo, woh, wol, 256, 256, 6, 65536, 0);
    T(Wvp, wvph, wvpl, 256, 256, 6, 65536, 0);
    T(Woff, wfah, wfal, 256, 192, 6, 81920, 0);
    T(Waw, wfah, wfal, 256, 96, 6, 81920, 192);
    T(Wop, woph, wopl, 256, 256, 6, 65536, 0);
    T(Wff1, wf1h, wf1l, 256, 1024, 6, 262144, 0);
    T(Wff2, wf2h, wf2l, 1024, 256, 6, 262144, 0);
    T(Wb1, wb1h, wb1l, 256, 256, 6, 65536, 0);
    T(Wb2, wb2h, wb2l, 256, 256, 6, 65536, 0);
    T(Wb3, wb3h, wb3l, 256, 4, 6, 1024, 0);
    T(Ws, wsh, wsl, 256, 80, 6, 20480, 0);
    T(Wp1, wp1h, wp1l, 4, 512, 1, 131072, 0);
    T(Wp2, wp2h, wp2l, 512, 256, 1, 131072, 0);
    concat2_kernel<<<12, 256, 0, stream>>>(bq, 256, bk, 256, bqk, 6);
    concat2_kernel<<<7, 256, 0, stream>>>(boff, 192, baw, 96, bfa, 6);

    hipMemcpyAsync(out_f, tgt, (size_t)NROW * DM * 4, hipMemcpyDeviceToDevice, stream);
    init_ref_kernel<<<75, 256, 0, stream>>>(rpu, refd_f, NROW * 4);

    auto G = [&](const float* A, const ushort* BTh, const ushort* BTl,
                 const float* bias, float* C, int M, int N, int K, bool relu) {
        dim3 g(M / 64, (N + 63) / 64);
        if (relu) gemm_sp<1, float><<<g, 256, 0, stream>>>(A, BTh, BTl, bias, C, M, N, K);
        else      gemm_sp<0, float><<<g, 256, 0, stream>>>(A, BTh, BTl, bias, C, M, N, K);
    };

    for (int i = 0; i < NLAYERS; ++i) {
        // qpos = relu(ref_d @ Wp1 + bp1) @ Wp2 + bp2
        G(refd_f, wp1h, wp1l, bp1, t1_f, NROW, 512, 4, true);
        G(t1_f, wp2h, wp2l, bp2, qpos_f, NROW, 256, 512, false);
        prep_kernel<<<4800, 256, 0, stream>>>(out_f, qpos_f, q_f, NROW * DM);
        // MHA (Q|K fused)
        G(q_f, wqkh + i * 131072, wqkl + i * 131072, bqk + i * 512, qk_f, NROW, 512, 256, false);
        G(out_f, wvh + i * 65536, wvl + i * 65536, bv + i * 256, vh_f, NROW, 256, 256, false);
        mha_mfma_kernel<<<256, 256, 0, stream>>>(qk_f, 512, qk_f + 256, 512, vh_f, 256, att_f);
        G(att_f, woh + i * 65536, wol + i * 65536, bo + i * 256, tmp_f, NROW, 256, 256, false);
        addln_kernel<<<1200, 256, 0, stream>>>(out_f, tmp_f, ln1g + i * 256, ln1b + i * 256,
                                               out_f, qpos_f, q2_f);
        // Deformable attention: fat-tile value projection (bf16-grade)
        {
            dim3 g(DM / 128, (BSZ * LVTOT) / 128);
            gemm_big<<<g, 256, 0, stream>>>(memory, wvph + i * 65536, bvp + i * 256,
                                            val_bf, BSZ * LVTOT, DM, DM);
        }
        G(q2_f, wfah + i * 81920, wfal + i * 81920, bfa + i * 288, offaw_f, NROW, 288, 256, false);
        deform_kernel<<<4800, 256, 0, stream>>>(val_bf, offaw_f, refd_f, samp_f);
        G(samp_f, woph + i * 65536, wopl + i * 65536, bop + i * 256, tmp_f, NROW, 256, 256, false);
        addln_kernel<<<1200, 256, 0, stream>>>(out_f, tmp_f, ln2g + i * 256, ln2b + i * 256,
                                               out_f, nullptr, nullptr);
        // FFN
        G(out_f, wf1h + i * 262144, wf1l + i * 262144, bff1 + i * 1024, ff_f, NROW, 1024, 256, true);
        G(ff_f, wf2h + i * 262144, wf2l + i * 262144, bff2 + i * 256, tmp_f, NROW, 256, 1024, false);
        addln_kernel<<<1200, 256, 0, stream>>>(out_f, tmp_f, ln3g + i * 256, ln3b + i * 256,
                                               out_f, nullptr, nullptr);
        // bbox head
        G(out_f, wb1h + i * 65536, wb1l + i * 65536, bb1 + i * 256, h1_f, NROW, 256, 256, true);
        G(h1_f, wb2h + i * 65536, wb2l + i * 65536, bb2 + i * 256, h2_f, NROW, 256, 256, true);
        G(h2_f, wb3h + i * 1024, wb3l + i * 1024, bb3 + i * 4, b3_f, NROW, 4, 256, false);
        refupd_kernel<<<75, 256, 0, stream>>>(b3_f, refd_f, (float*)d_out,
                                              (i == NLAYERS - 1) ? 1 : 0);
        if (i == NLAYERS - 1) {
            G(out_f, wsh + i * 20480, wsl + i * 20480, bs_ + i * 80,
              (float*)d_out + NROW * 4, NROW, 80, 256, false);
        }
    }
}

// Round 6
// 2335.200 us; speedup vs baseline: 1.8916x; 1.0640x over previous
//
#include <hip/hip_runtime.h>

#define NLAYERS 6
#define BSZ 16
#define NQL 300
#define DM 256
#define NHEAD 8
#define HDIM 32
#define NLVL 3
#define NPT 4
#define DFFN 1024
#define NCLS 80
#define LVTOT 8400
#define NROW (BSZ * NQL)   // 4800
#define MEMN (BSZ * LVTOT) // 134400

typedef __attribute__((ext_vector_type(8))) short bf16x8;
typedef __attribute__((ext_vector_type(8))) ushort us8;
typedef __attribute__((ext_vector_type(4))) float f32x4;

__device__ __forceinline__ float b2f(ushort u) {
    return __uint_as_float(((uint)u) << 16);
}
__device__ __forceinline__ ushort f2b(float f) {
    uint i = __float_as_uint(f);
    uint r = i + 0x7fffu + ((i >> 16) & 1u);   // RNE
    return (ushort)(r >> 16);
}
__device__ __forceinline__ void split2(float v, ushort& h, ushort& l) {
    ushort hh = f2b(v);
    h = hh;
    l = f2b(v - b2f(hh));
}
// async global -> LDS, 16 bytes per lane
__device__ __forceinline__ void gl_lds16(const void* g, void* l) {
    __builtin_amdgcn_global_load_lds(
        (const __attribute__((address_space(1))) unsigned int*)g,
        (__attribute__((address_space(3))) unsigned int*)l, 16, 0, 0);
}

// ---------------------------------------------------------------------------
// fp32 -> bf16 plane (4 elems/thread)
// ---------------------------------------------------------------------------
__global__ __launch_bounds__(256) void f2b_kernel(
    const float* __restrict__ src, ushort* __restrict__ dst, int n)
{
    int i = (blockIdx.x * 256 + threadIdx.x) * 4;
    if (i < n) {
        float4 v = *(const float4*)&src[i];
        ushort4 o = {f2b(v.x), f2b(v.y), f2b(v.z), f2b(v.w)};
        *(ushort4*)&dst[i] = o;
    }
}

// ---------------------------------------------------------------------------
// Batched transpose + bf16 split: src fp32 (B,K,N) -> dst (B, drow0+N, K)
// lo plane optional (dl may be null).
// ---------------------------------------------------------------------------
__global__ __launch_bounds__(256) void transpose_split_kernel(
    const float* __restrict__ src, ushort* __restrict__ dh,
    ushort* __restrict__ dl, int K, int N, int dlstride, int drow0)
{
    __shared__ float tile[32][33];
    src += (size_t)blockIdx.z * (size_t)K * (size_t)N;
    const size_t doff = (size_t)blockIdx.z * dlstride + (size_t)drow0 * K;
    dh += doff;
    if (dl) dl += doff;
    const int n0 = blockIdx.x * 32, k0 = blockIdx.y * 32;
    const int tx = threadIdx.x, ty = threadIdx.y;   // 32 x 8
    for (int r = 0; r < 32; r += 8) {
        int k = k0 + ty + r, n = n0 + tx;
        if (k < K && n < N) tile[ty + r][tx] = src[(size_t)k * N + n];
    }
    __syncthreads();
    for (int r = 0; r < 32; r += 8) {
        int n = n0 + ty + r, k = k0 + tx;
        if (n < N && k < K) {
            ushort h, l;
            split2(tile[tx][ty + r], h, l);
            dh[(size_t)n * K + k] = h;
            if (dl) dl[(size_t)n * K + k] = l;
        }
    }
}

// ---------------------------------------------------------------------------
// Bias concat
// ---------------------------------------------------------------------------
__global__ __launch_bounds__(256) void concat2_kernel(
    const float* __restrict__ a, int na, const float* __restrict__ b, int nb,
    float* __restrict__ dst, int nl)
{
    const int tot = na + nb;
    int i = blockIdx.x * 256 + threadIdx.x;
    if (i < nl * tot) {
        int l = i / tot, j = i - l * tot;
        dst[i] = (j < na) ? a[l * na + j] : b[l * nb + j - na];
    }
}

// ---------------------------------------------------------------------------
// Split-A MFMA GEMM (64x64): C = act(A@B + bias); A fp32 split hi/lo in-kernel,
// B weights bf16-hi only. D = Ah*Bh + Al*Bh. Optional fused out2 = C + addsrc.
// ---------------------------------------------------------------------------
template <int ACT>
__global__ __launch_bounds__(256) void gemm_sp(
    const float* __restrict__ A, const ushort* __restrict__ BTh,
    const float* __restrict__ bias, float* __restrict__ C,
    int M, int N, int K,
    const float* __restrict__ addsrc, float* __restrict__ out2)
{
    __shared__ __align__(16) ushort Ah[64 * 40];
    __shared__ __align__(16) ushort Al[64 * 40];
    __shared__ __align__(16) ushort Bh[64 * 40];

    const int tid  = threadIdx.x;
    const int m0   = blockIdx.x * 64;
    const int n0   = blockIdx.y * 64;
    const int wv   = tid >> 6;
    const int lane = tid & 63;
    const int lm   = lane & 15;
    const int lq   = lane >> 4;
    const int r    = tid >> 2;
    const int c8   = (tid & 3) * 8;

    f32x4 acc[4] = {};

    for (int k0 = 0; k0 < K; k0 += 32) {
        __syncthreads();
        {
            float av[8];
            if (k0 + 32 <= K) {
                *(float4*)&av[0] = *(const float4*)&A[(size_t)(m0 + r) * K + k0 + c8];
                *(float4*)&av[4] = *(const float4*)&A[(size_t)(m0 + r) * K + k0 + c8 + 4];
            } else {
#pragma unroll
                for (int j = 0; j < 8; ++j) {
                    int k = k0 + c8 + j;
                    av[j] = (k < K) ? A[(size_t)(m0 + r) * K + k] : 0.f;
                }
            }
            us8 hv, lv;
#pragma unroll
            for (int j = 0; j < 8; ++j) {
                ushort h, l;
                split2(av[j], h, l);
                hv[j] = h; lv[j] = l;
            }
            *(us8*)&Ah[r * 40 + c8] = hv;
            *(us8*)&Al[r * 40 + c8] = lv;
        }
        if (n0 + r < N && k0 + 32 <= K) {
            *(uint4*)&Bh[r * 40 + c8] = *(const uint4*)&BTh[(size_t)(n0 + r) * K + k0 + c8];
        } else if (n0 + r < N) {
#pragma unroll
            for (int j = 0; j < 8; ++j) {
                int k = k0 + c8 + j;
                Bh[r * 40 + c8 + j] = (k < K) ? BTh[(size_t)(n0 + r) * K + k] : (ushort)0;
            }
        } else {
            uint4 z = {0, 0, 0, 0};
            *(uint4*)&Bh[r * 40 + c8] = z;
        }
        __syncthreads();

        bf16x8 afh = *(const bf16x8*)&Ah[(wv * 16 + lm) * 40 + lq * 8];
        bf16x8 afl = *(const bf16x8*)&Al[(wv * 16 + lm) * 40 + lq * 8];
#pragma unroll
        for (int nb = 0; nb < 4; ++nb) {
            bf16x8 bfh = *(const bf16x8*)&Bh[(nb * 16 + lm) * 40 + lq * 8];
            acc[nb] = __builtin_amdgcn_mfma_f32_16x16x32_bf16(afh, bfh, acc[nb], 0, 0, 0);
            acc[nb] = __builtin_amdgcn_mfma_f32_16x16x32_bf16(afl, bfh, acc[nb], 0, 0, 0);
        }
    }

    const int row = m0 + wv * 16 + lq * 4;
#pragma unroll
    for (int nb = 0; nb < 4; ++nb) {
        int col = n0 + nb * 16 + lm;
        if (col < N) {
            float bv = bias ? bias[col] : 0.f;
#pragma unroll
            for (int rr = 0; rr < 4; ++rr) {
                float v = acc[nb][rr] + bv;
                if (ACT) v = fmaxf(v, 0.f);
                const size_t idx = (size_t)(row + rr) * N + col;
                C[idx] = v;
                if (out2) out2[idx] = v + addsrc[idx];
            }
        }
    }
}

// ---------------------------------------------------------------------------
// Fat-tile bf16 GEMM (128x128, 4 waves, 4x4 acc): C bf16 = Abf @ BTh^T + bias.
// A pre-converted bf16. Staging via global_load_lds (8 segs of 1KB per tile).
// M%128==0, N%128==0, K%32==0. Grid (N/128, M/128).
// ---------------------------------------------------------------------------
__global__ __launch_bounds__(256) void gemm_big(
    const ushort* __restrict__ Abf, const ushort* __restrict__ BTh,
    const float* __restrict__ bias, ushort* __restrict__ C,
    int M, int N, int K)
{
    __shared__ __align__(16) ushort As[128 * 32];
    __shared__ __align__(16) ushort Bs[128 * 32];
    const int tid = threadIdx.x;
    const int n0 = blockIdx.x * 128, m0 = blockIdx.y * 128;
    const int wv = tid >> 6, lane = tid & 63;
    const int lm = lane & 15, quad = lane >> 4;
    const int wr = wv >> 1, wc = wv & 1;
    const int srow = lane >> 2;            // 0..15 row within 1KB segment
    const int scol = (lane & 3) * 8;       // 8-ushort chunk

    f32x4 acc[4][4] = {};

    for (int k0 = 0; k0 < K; k0 += 32) {
        __syncthreads();
#pragma unroll
        for (int s2 = 0; s2 < 2; ++s2) {
            const int seg = wv * 2 + s2;           // 0..7
            const int row = seg * 16 + srow;       // 0..127
            gl_lds16(&Abf[(size_t)(m0 + row) * K + k0 + scol],
                     &As[seg * 512 + lane * 8]);
            gl_lds16(&BTh[(size_t)(n0 + row) * K + k0 + scol],
                     &Bs[seg * 512 + lane * 8]);
        }
        __syncthreads();

        bf16x8 af[4], bfr[4];
#pragma unroll
        for (int i = 0; i < 4; ++i)
            af[i] = *(const bf16x8*)&As[(wr * 64 + i * 16 + lm) * 32 + quad * 8];
#pragma unroll
        for (int i = 0; i < 4; ++i)
            bfr[i] = *(const bf16x8*)&Bs[(wc * 64 + i * 16 + lm) * 32 + quad * 8];
#pragma unroll
        for (int mi = 0; mi < 4; ++mi)
#pragma unroll
            for (int ni = 0; ni < 4; ++ni)
                acc[mi][ni] = __builtin_amdgcn_mfma_f32_16x16x32_bf16(
                    af[mi], bfr[ni], acc[mi][ni], 0, 0, 0);
    }

#pragma unroll
    for (int ni = 0; ni < 4; ++ni) {
        const int col = n0 + wc * 64 + ni * 16 + lm;
        const float bv = bias[col];
#pragma unroll
        for (int mi = 0; mi < 4; ++mi) {
            const int row = m0 + wr * 64 + mi * 16 + quad * 4;
#pragma unroll
            for (int rr = 0; rr < 4; ++rr)
                C[(size_t)(row + rr) * N + col] = f2b(acc[mi][ni][rr] + bv);
        }
    }
}

// ---------------------------------------------------------------------------
// MFMA MHA: one block per (b, h, q-half); strided q/k/v.
// ---------------------------------------------------------------------------
__global__ __launch_bounds__(256) void mha_mfma_kernel(
    const float* __restrict__ qh, int ldq, const float* __restrict__ kh, int ldk,
    const float* __restrict__ vh, int ldv, float* __restrict__ outp)
{
    __shared__ ushort Kh[304 * 36];
    __shared__ ushort Vth[32 * 328];
    __shared__ ushort Pb[4][16 * 168];

    const int tid = threadIdx.x;
    const int wv = tid >> 6, lane = tid & 63;
    const int bh = blockIdx.x >> 1, half = blockIdx.x & 1;
    const int b = bh >> 3, h = bh & 7;
    const size_t qbase = (size_t)b * NQL * ldq + h * HDIM;
    const size_t kbase = (size_t)b * NQL * ldk + h * HDIM;
    const size_t vbase = (size_t)b * NQL * ldv + h * HDIM;
    const size_t obase = (size_t)b * NQL * DM + h * HDIM;

    for (int idx = tid; idx < 304 * 32; idx += 256) {
        int row = idx >> 5, d = idx & 31;
        float v = (row < NQL) ? kh[kbase + (size_t)row * ldk + d] : 0.f;
        Kh[row * 36 + d] = f2b(v);
    }
    for (int idx = tid; idx < 328 * 32; idx += 256) {
        int key = idx >> 5, d = idx & 31;
        float v = (key < NQL) ? vh[vbase + (size_t)key * ldv + d] : 0.f;
        Vth[d * 328 + key] = f2b(v);
    }
    for (int i = lane; i < 16 * 168; i += 64) Pb[wv][i] = 0;
    __syncthreads();

    const int quad = lane >> 4, c = lane & 15;
    const float scale = 0.17677669529663687f;

    const int qt_beg = (half ? 10 : 0) + wv;
    const int qt_end = (half ? 19 : 10);
    for (int qt = qt_beg; qt < qt_end; qt += 4) {
        const int q = qt * 16 + c;
        const float* qrow = qh + qbase + (size_t)q * ldq + quad * 8;
        float qv[8];
        *(float4*)&qv[0] = *(const float4*)qrow;
        *(float4*)&qv[4] = *(const float4*)(qrow + 4);
        bf16x8 qf;
#pragma unroll
        for (int j = 0; j < 8; ++j) ((ushort*)&qf)[j] = f2b(qv[j]);

        f32x4 sc[19];
#pragma unroll
        for (int kt = 0; kt < 19; ++kt) {
            bf16x8 kf = *(const bf16x8*)&Kh[(kt * 16 + c) * 36 + quad * 8];
            f32x4 a = {};
            a = __builtin_amdgcn_mfma_f32_16x16x32_bf16(qf, kf, a, 0, 0, 0);
            sc[kt] = a;
        }
        float inv4[4];
#pragma unroll
        for (int r = 0; r < 4; ++r) {
            float mx = -1e30f;
#pragma unroll
            for (int kt = 0; kt < 19; ++kt) {
                float s = sc[kt][r] * scale;
                if (kt * 16 + c >= NQL) s = -1e30f;
                sc[kt][r] = s;
                mx = fmaxf(mx, s);
            }
#pragma unroll
            for (int m = 1; m < 16; m <<= 1) mx = fmaxf(mx, __shfl_xor(mx, m, 64));
            float l = 0.f;
#pragma unroll
            for (int kt = 0; kt < 19; ++kt) {
                float p = __expf(sc[kt][r] - mx);
                sc[kt][r] = p;
                l += p;
            }
#pragma unroll
            for (int m = 1; m < 16; m <<= 1) l += __shfl_xor(l, m, 64);
            inv4[r] = 1.f / l;
        }

        f32x4 o0 = {}, o1 = {};
#pragma unroll
        for (int r = 0; r < 4; ++r)
#pragma unroll
            for (int kt = 0; kt < 10; ++kt)
                Pb[wv][(quad * 4 + r) * 168 + kt * 16 + c] = f2b(sc[kt][r] * inv4[r]);
#pragma unroll
        for (int ks = 0; ks < 5; ++ks) {
            bf16x8 pf = *(const bf16x8*)&Pb[wv][c * 168 + ks * 32 + quad * 8];
            bf16x8 v0 = *(const bf16x8*)&Vth[c * 328 + ks * 32 + quad * 8];
            bf16x8 v1 = *(const bf16x8*)&Vth[(16 + c) * 328 + ks * 32 + quad * 8];
            o0 = __builtin_amdgcn_mfma_f32_16x16x32_bf16(pf, v0, o0, 0, 0, 0);
            o1 = __builtin_amdgcn_mfma_f32_16x16x32_bf16(pf, v1, o1, 0, 0, 0);
        }
#pragma unroll
        for (int r = 0; r < 4; ++r) {
#pragma unroll
            for (int kt = 10; kt < 19; ++kt)
                Pb[wv][(quad * 4 + r) * 168 + (kt - 10) * 16 + c] = f2b(sc[kt][r] * inv4[r]);
            Pb[wv][(quad * 4 + r) * 168 + 144 + c] = 0;
        }
#pragma unroll
        for (int ks = 0; ks < 5; ++ks) {
            bf16x8 pf = *(const bf16x8*)&Pb[wv][c * 168 + ks * 32 + quad * 8];
            bf16x8 v0 = *(const bf16x8*)&Vth[c * 328 + 160 + ks * 32 + quad * 8];
            bf16x8 v1 = *(const bf16x8*)&Vth[(16 + c) * 328 + 160 + ks * 32 + quad * 8];
            o0 = __builtin_amdgcn_mfma_f32_16x16x32_bf16(pf, v0, o0, 0, 0, 0);
            o1 = __builtin_amdgcn_mfma_f32_16x16x32_bf16(pf, v1, o1, 0, 0, 0);
        }
#pragma unroll
        for (int r = 0; r < 4; ++r) {
            const int qq = qt * 16 + quad * 4 + r;
            if (qq < NQL) {
                outp[obase + (size_t)qq * DM + c] = o0[r];
                outp[obase + (size_t)qq * DM + 16 + c] = o1[r];
            }
        }
    }
}

// ---------------------------------------------------------------------------
// Deformable sampling. offaw: per row 288 = 192 offsets + 96 aw logits.
// ---------------------------------------------------------------------------
__global__ __launch_bounds__(256) void deform_kernel(
    const ushort* __restrict__ val, const float* __restrict__ offaw,
    const float* __restrict__ refd, float* __restrict__ outp)
{
    __shared__ float offs[192];
    __shared__ float aws[96];
    __shared__ float rr[4];
    const int row = blockIdx.x;
    const int b = row / NQL;
    const int t = threadIdx.x;
    if (t < 192) offs[t] = offaw[(size_t)row * 288 + t];
    if (t < 96)  aws[t] = offaw[(size_t)row * 288 + 192 + t];
    if (t < 4)   rr[t] = refd[row * 4 + t];
    __syncthreads();

    const int h = t >> 5, d = t & 31;
    float mx = -1e30f;
#pragma unroll
    for (int j = 0; j < 12; ++j) mx = fmaxf(mx, aws[h * 12 + j]);
    float ev[12]; float se = 0.f;
#pragma unroll
    for (int j = 0; j < 12; ++j) { ev[j] = __expf(aws[h * 12 + j] - mx); se += ev[j]; }
    const float inv = 1.f / se;

    const int HWs[3] = {80, 40, 20};
    const int STs[3] = {0, 6400, 8000};
    float acc = 0.f;
#pragma unroll
    for (int l = 0; l < NLVL; ++l) {
        const int Wd = HWs[l], Hd = HWs[l], st = STs[l];
#pragma unroll
        for (int p = 0; p < NPT; ++p) {
            const float w12 = ev[l * 4 + p] * inv;
            const float ox = offs[((h * 3 + l) * 4 + p) * 2 + 0];
            const float oy = offs[((h * 3 + l) * 4 + p) * 2 + 1];
            const float x = (rr[0] + ox * 0.125f * rr[2]) * Wd - 0.5f;
            const float y = (rr[1] + oy * 0.125f * rr[3]) * Hd - 0.5f;
            const float xf = floorf(x), yf = floorf(y);
            const int x0 = (int)xf, y0 = (int)yf;
            const float wx = x - xf, wy = y - yf;
            const float tw[4] = {(1 - wx) * (1 - wy), wx * (1 - wy),
                                 (1 - wx) * wy,       wx * wy};
            const int xs[4] = {x0, x0 + 1, x0, x0 + 1};
            const int ys[4] = {y0, y0, y0 + 1, y0 + 1};
            float sv = 0.f;
#pragma unroll
            for (int tp = 0; tp < 4; ++tp) {
                const int xi = xs[tp], yi = ys[tp];
                if (xi >= 0 && xi < Wd && yi >= 0 && yi < Hd) {
                    const int idx = st + yi * Wd + xi;
                    sv += tw[tp] * b2f(val[((size_t)b * LVTOT + idx) * DM + h * HDIM + d]);
                }
            }
            acc += w12 * sv;
        }
    }
    outp[(size_t)row * DM + t] = acc;
}

// ---------------------------------------------------------------------------
// Fused residual add + LayerNorm (fp32). One wave per row.
// ---------------------------------------------------------------------------
__global__ __launch_bounds__(256) void addln_kernel(
    const float* x, const float* __restrict__ dl,
    const float* __restrict__ g, const float* __restrict__ bb,
    float* outf, const float* __restrict__ qpos, float* __restrict__ q2)
{
    const int wv = threadIdx.x >> 6, lane = threadIdx.x & 63;
    const int row = blockIdx.x * 4 + wv;
    const size_t base = (size_t)row * DM + lane * 4;
    const float4 xv = *(const float4*)(x + base);
    const float4 dv = *(const float4*)(dl + base);
    float v[4] = {xv.x + dv.x, xv.y + dv.y, xv.z + dv.z, xv.w + dv.w};

    float s = v[0] + v[1] + v[2] + v[3];
#pragma unroll
    for (int m = 32; m; m >>= 1) s += __shfl_xor(s, m, 64);
    const float mean = s * (1.f / 256.f);
    float sq = 0.f;
#pragma unroll
    for (int j = 0; j < 4; ++j) { float dd = v[j] - mean; sq += dd * dd; }
#pragma unroll
    for (int m = 32; m; m >>= 1) sq += __shfl_xor(sq, m, 64);
    const float rstd = rsqrtf(sq * (1.f / 256.f) + 1e-5f);

    float y[4];
#pragma unroll
    for (int j = 0; j < 4; ++j) {
        const int col = lane * 4 + j;
        y[j] = (v[j] - mean) * rstd * g[col] + bb[col];
    }
    *(float4*)(outf + base) = make_float4(y[0], y[1], y[2], y[3]);
    if (q2) {
        const float4 qp = *(const float4*)(qpos + base);
        *(float4*)(q2 + base) = make_float4(y[0] + qp.x, y[1] + qp.y,
                                            y[2] + qp.z, y[3] + qp.w);
    }
}

// ---------------------------------------------------------------------------
// Small elementwise kernels
// ---------------------------------------------------------------------------
__global__ __launch_bounds__(256) void init_ref_kernel(
    const float* __restrict__ rpu, float* __restrict__ refd, int n)
{
    int i = blockIdx.x * 256 + threadIdx.x;
    if (i < n) refd[i] = 1.f / (1.f + __expf(-rpu[i]));
}

__global__ __launch_bounds__(256) void refupd_kernel(
    const float* __restrict__ b3, float* __restrict__ refd,
    float* __restrict__ dout, int writeout)
{
    int i = blockIdx.x * 256 + threadIdx.x;
    if (i < NROW * 4) {
        float r = fminf(fmaxf(refd[i], 0.f), 1.f);
        float invs = logf(fmaxf(r, 1e-5f)) - logf(fmaxf(1.f - r, 1e-5f));
        float v = 1.f / (1.f + __expf(-(b3[i] + invs)));
        refd[i] = v;
        if (writeout) dout[i] = v;
    }
}

// ---------------------------------------------------------------------------
// Host launch
// ---------------------------------------------------------------------------
extern "C" void kernel_launch(void* const* d_in, const int* in_sizes, int n_in,
                              void* d_out, int out_size, void* d_ws, size_t ws_size,
                              hipStream_t stream)
{
    const float* tgt    = (const float*)d_in[0];
    const float* rpu    = (const float*)d_in[1];
    const float* memory = (const float*)d_in[2];
    const float* Wq  = (const float*)d_in[5];  const float* bq  = (const float*)d_in[6];
    const float* Wk  = (const float*)d_in[7];  const float* bk  = (const float*)d_in[8];
    const float* Wv  = (const float*)d_in[9];  const float* bv  = (const float*)d_in[10];
    const float* Wo  = (const float*)d_in[11]; const float* bo  = (const float*)d_in[12];
    const float* ln1g = (const float*)d_in[13]; const float* ln1b = (const float*)d_in[14];
    const float* ln2g = (const float*)d_in[15]; const float* ln2b = (const float*)d_in[16];
    const float* ln3g = (const float*)d_in[17]; const float* ln3b = (const float*)d_in[18];
    const float* Wvp = (const float*)d_in[19]; const float* bvp = (const float*)d_in[20];
    const float* Woff = (const float*)d_in[21]; const float* boff = (const float*)d_in[22];
    const float* Waw = (const float*)d_in[23]; const float* baw = (const float*)d_in[24];
    const float* Wop = (const float*)d_in[25]; const float* bop = (const float*)d_in[26];
    const float* Wff1 = (const float*)d_in[27]; const float* bff1 = (const float*)d_in[28];
    const float* Wff2 = (const float*)d_in[29]; const float* bff2 = (const float*)d_in[30];
    const float* Wb1 = (const float*)d_in[31]; const float* bb1 = (const float*)d_in[32];
    const float* Wb2 = (const float*)d_in[33]; const float* bb2 = (const float*)d_in[34];
    const float* Wb3 = (const float*)d_in[35]; const float* bb3 = (const float*)d_in[36];
    const float* Ws  = (const float*)d_in[37]; const float* bs_ = (const float*)d_in[38];
    const float* Wp1 = (const float*)d_in[39]; const float* bp1 = (const float*)d_in[40];
    const float* Wp2 = (const float*)d_in[41]; const float* bp2 = (const float*)d_in[42];

    size_t off = 0;
    auto alloc = [&](size_t elems, size_t elsz) -> void* {
        void* r = (char*)d_ws + off;
        off += elems * elsz;
        off = (off + 255) & ~(size_t)255;
        return r;
    };
    // weight planes (bf16-hi only), transposed to (N x K); Q|K and off|aw fused
    ushort *wqkh = (ushort*)alloc(6 * 131072, 2);
    ushort *wvh  = (ushort*)alloc(6 * 65536, 2);
    ushort *woh  = (ushort*)alloc(6 * 65536, 2);
    ushort *wvph = (ushort*)alloc(6 * 65536, 2);
    ushort *wfah = (ushort*)alloc(6 * 81920, 2);
    ushort *woph = (ushort*)alloc(6 * 65536, 2);
    ushort *wf1h = (ushort*)alloc(6 * 262144, 2);
    ushort *wf2h = (ushort*)alloc(6 * 262144, 2);
    ushort *wb1h = (ushort*)alloc(6 * 65536, 2);
    ushort *wb2h = (ushort*)alloc(6 * 65536, 2);
    ushort *wb3h = (ushort*)alloc(6 * 1024, 2);
    ushort *wsh  = (ushort*)alloc(6 * 20480, 2);
    ushort *wp1h = (ushort*)alloc(2048, 2);
    ushort *wp2h = (ushort*)alloc(131072, 2);
    float  *bqk  = (float*)alloc(6 * 512, 4);
    float  *bfa  = (float*)alloc(6 * 288, 4);

    ushort* mem_bf = (ushort*)alloc((size_t)MEMN * DM, 2);   // 68.8 MB
    ushort* val_bf = (ushort*)alloc((size_t)MEMN * DM, 2);   // 68.8 MB
    float*  out_f  = (float*)alloc(NROW * DM, 4);
    float*  qpos_f = (float*)alloc(NROW * DM, 4);
    float*  q_f    = (float*)alloc(NROW * DM, 4);
    float*  q2_f   = (float*)alloc(NROW * DM, 4);
    float*  tmp_f  = (float*)alloc(NROW * DM, 4);
    float*  b3_f   = (float*)alloc(NROW * 4, 4);
    float*  refd_f = (float*)alloc(NROW * 4, 4);
    float* arena = (float*)alloc(NROW * 1024, 4);   // phase-disjoint
    float* t1_f    = arena;                          // 4800 x 512
    float* qk_f    = arena;                          // 4800 x 512
    float* vh_f    = arena + NROW * 512;             // 4800 x 256
    float* att_f   = arena + NROW * 768;             // 4800 x 256
    float* offaw_f = arena;                          // 4800 x 288
    float* samp_f  = arena + NROW * 288;             // 4800 x 256
    float* ff_f    = arena;                          // 4800 x 1024
    float* h1_f    = arena;                          // 4800 x 256
    float* h2_f    = arena + NROW * DM;              // 4800 x 256

    if (off > ws_size) return;

    dim3 tb(32, 8);
    auto T = [&](const float* s, ushort* dh, int K, int N, int B, int dls, int dr0) {
        dim3 g((N + 31) / 32, (K + 31) / 32, B);
        transpose_split_kernel<<<g, tb, 0, stream>>>(s, dh, nullptr, K, N, dls, dr0);
    };
    T(Wq, wqkh, 256, 256, 6, 131072, 0);
    T(Wk, wqkh, 256, 256, 6, 131072, 256);
    T(Wv, wvh, 256, 256, 6, 65536, 0);
    T(Wo, woh, 256, 256, 6, 65536, 0);
    T(Wvp, wvph, 256, 256, 6, 65536, 0);
    T(Woff, wfah, 256, 192, 6, 81920, 0);
    T(Waw, wfah, 256, 96, 6, 81920, 192);
    T(Wop, woph, 256, 256, 6, 65536, 0);
    T(Wff1, wf1h, 256, 1024, 6, 262144, 0);
    T(Wff2, wf2h, 1024, 256, 6, 262144, 0);
    T(Wb1, wb1h, 256, 256, 6, 65536, 0);
    T(Wb2, wb2h, 256, 256, 6, 65536, 0);
    T(Wb3, wb3h, 256, 4, 6, 1024, 0);
    T(Ws, wsh, 256, 80, 6, 20480, 0);
    T(Wp1, wp1h, 4, 512, 1, 131072, 0);
    T(Wp2, wp2h, 512, 256, 1, 131072, 0);
    concat2_kernel<<<12, 256, 0, stream>>>(bq, 256, bk, 256, bqk, 6);
    concat2_kernel<<<7, 256, 0, stream>>>(boff, 192, baw, 96, bfa, 6);
    f2b_kernel<<<(MEMN * DM) / 1024, 256, 0, stream>>>(memory, mem_bf, MEMN * DM);

    hipMemcpyAsync(out_f, tgt, (size_t)NROW * DM * 4, hipMemcpyDeviceToDevice, stream);
    init_ref_kernel<<<75, 256, 0, stream>>>(rpu, refd_f, NROW * 4);

    auto G = [&](const float* A, const ushort* BTh, const float* bias,
                 float* C, int M, int N, int K, bool relu,
                 const float* addsrc = nullptr, float* out2 = nullptr) {
        dim3 g(M / 64, (N + 63) / 64);
        if (relu) gemm_sp<1><<<g, 256, 0, stream>>>(A, BTh, bias, C, M, N, K, addsrc, out2);
        else      gemm_sp<0><<<g, 256, 0, stream>>>(A, BTh, bias, C, M, N, K, addsrc, out2);
    };

    for (int i = 0; i < NLAYERS; ++i) {
        // qpos = relu(ref_d @ Wp1 + bp1) @ Wp2 + bp2;  q = out + qpos (fused)
        G(refd_f, wp1h, bp1, t1_f, NROW, 512, 4, true);
        G(t1_f, wp2h, bp2, qpos_f, NROW, 256, 512, false, out_f, q_f);
        // MHA (Q|K fused)
        G(q_f, wqkh + i * 131072, bqk + i * 512, qk_f, NROW, 512, 256, false);
        G(out_f, wvh + i * 65536, bv + i * 256, vh_f, NROW, 256, 256, false);
        mha_mfma_kernel<<<256, 256, 0, stream>>>(qk_f, 512, qk_f + 256, 512, vh_f, 256, att_f);
        G(att_f, woh + i * 65536, bo + i * 256, tmp_f, NROW, 256, 256, false);
        addln_kernel<<<1200, 256, 0, stream>>>(out_f, tmp_f, ln1g + i * 256, ln1b + i * 256,
                                               out_f, qpos_f, q2_f);
        // Deformable attention: fat-tile bf16 value projection
        {
            dim3 g(DM / 128, MEMN / 128);
            gemm_big<<<g, 256, 0, stream>>>(mem_bf, wvph + i * 65536, bvp + i * 256,
                                            val_bf, MEMN, DM, DM);
        }
        G(q2_f, wfah + i * 81920, bfa + i * 288, offaw_f, NROW, 288, 256, false);
        deform_kernel<<<4800, 256, 0, stream>>>(val_bf, offaw_f, refd_f, samp_f);
        G(samp_f, woph + i * 65536, bop + i * 256, tmp_f, NROW, 256, 256, false);
        addln_kernel<<<1200, 256, 0, stream>>>(out_f, tmp_f, ln2g + i * 256, ln2b + i * 256,
                                               out_f, nullptr, nullptr);
        // FFN
        G(out_f, wf1h + i * 262144, bff1 + i * 1024, ff_f, NROW, 1024, 256, true);
        G(ff_f, wf2h + i * 262144, bff2 + i * 256, tmp_f, NROW, 256, 1024, false);
        addln_kernel<<<1200, 256, 0, stream>>>(out_f, tmp_f, ln3g + i * 256, ln3b + i * 256,
                                               out_f, nullptr, nullptr);
        // bbox head
        G(out_f, wb1h + i * 65536, bb1 + i * 256, h1_f, NROW, 256, 256, true);
        G(h1_f, wb2h + i * 65536, bb2 + i * 256, h2_f, NROW, 256, 256, true);
        G(h2_f, wb3h + i * 1024, bb3 + i * 4, b3_f, NROW, 4, 256, false);
        refupd_kernel<<<75, 256, 0, stream>>>(b3_f, refd_f, (float*)d_out,
                                              (i == NLAYERS - 1) ? 1 : 0);
        if (i == NLAYERS - 1) {
            G(out_f, wsh + i * 20480, bs_ + i * 80,
              (float*)d_out + NROW * 4, NROW, 80, 256, false);
        }
    }
}

// Round 7
// 2159.093 us; speedup vs baseline: 2.0459x; 1.0816x over previous
//
#include <hip/hip_runtime.h>

#define NLAYERS 6
#define BSZ 16
#define NQL 300
#define DM 256
#define NHEAD 8
#define HDIM 32
#define NLVL 3
#define NPT 4
#define DFFN 1024
#define NCLS 80
#define LVTOT 8400
#define NROW (BSZ * NQL)   // 4800
#define MEMN (BSZ * LVTOT) // 134400

typedef __attribute__((ext_vector_type(8))) short bf16x8;
typedef __attribute__((ext_vector_type(8))) ushort us8;
typedef __attribute__((ext_vector_type(4))) float f32x4;

__device__ __forceinline__ float b2f(ushort u) {
    return __uint_as_float(((uint)u) << 16);
}
__device__ __forceinline__ ushort f2b(float f) {
    uint i = __float_as_uint(f);
    uint r = i + 0x7fffu + ((i >> 16) & 1u);   // RNE
    return (ushort)(r >> 16);
}
__device__ __forceinline__ void split2(float v, ushort& h, ushort& l) {
    ushort hh = f2b(v);
    h = hh;
    l = f2b(v - b2f(hh));
}
// async global -> LDS, 16 bytes per lane (LDS dest = wave base + lane*16)
__device__ __forceinline__ void gl_lds16(const void* g, void* l) {
    __builtin_amdgcn_global_load_lds(
        (const __attribute__((address_space(1))) unsigned int*)g,
        (__attribute__((address_space(3))) unsigned int*)l, 16, 0, 0);
}

// ---------------------------------------------------------------------------
// fp32 -> bf16 plane (4 elems/thread)
// ---------------------------------------------------------------------------
__global__ __launch_bounds__(256) void f2b_kernel(
    const float* __restrict__ src, ushort* __restrict__ dst, int n)
{
    int i = (blockIdx.x * 256 + threadIdx.x) * 4;
    if (i < n) {
        float4 v = *(const float4*)&src[i];
        ushort4 o = {f2b(v.x), f2b(v.y), f2b(v.z), f2b(v.w)};
        *(ushort4*)&dst[i] = o;
    }
}

// ---------------------------------------------------------------------------
// Batched transpose + bf16 hi: src fp32 (B,K,N) -> dst (B, drow0+N, K)
// ---------------------------------------------------------------------------
__global__ __launch_bounds__(256) void transpose_split_kernel(
    const float* __restrict__ src, ushort* __restrict__ dh,
    int K, int N, int dlstride, int drow0)
{
    __shared__ float tile[32][33];
    src += (size_t)blockIdx.z * (size_t)K * (size_t)N;
    const size_t doff = (size_t)blockIdx.z * dlstride + (size_t)drow0 * K;
    dh += doff;
    const int n0 = blockIdx.x * 32, k0 = blockIdx.y * 32;
    const int tx = threadIdx.x, ty = threadIdx.y;   // 32 x 8
    for (int r = 0; r < 32; r += 8) {
        int k = k0 + ty + r, n = n0 + tx;
        if (k < K && n < N) tile[ty + r][tx] = src[(size_t)k * N + n];
    }
    __syncthreads();
    for (int r = 0; r < 32; r += 8) {
        int n = n0 + ty + r, k = k0 + tx;
        if (n < N && k < K) dh[(size_t)n * K + k] = f2b(tile[tx][ty + r]);
    }
}

// ---------------------------------------------------------------------------
// Bias concat
// ---------------------------------------------------------------------------
__global__ __launch_bounds__(256) void concat2_kernel(
    const float* __restrict__ a, int na, const float* __restrict__ b, int nb,
    float* __restrict__ dst, int nl)
{
    const int tot = na + nb;
    int i = blockIdx.x * 256 + threadIdx.x;
    if (i < nl * tot) {
        int l = i / tot, j = i - l * tot;
        dst[i] = (j < na) ? a[l * na + j] : b[l * nb + j - na];
    }
}

// ---------------------------------------------------------------------------
// Pipelined split-A MFMA GEMM (64x64 tile, double-buffered LDS):
// C = act(A@B + bias); A fp32 (hi/lo split in-kernel), B bf16-hi (N x K).
// B staged async via global_load_lds; next A prefetched into regs during MFMA.
// D = Ah*Bh + Al*Bh. Optional fused out2 = C + addsrc.
// ---------------------------------------------------------------------------
template <int ACT>
__global__ __launch_bounds__(256) void gemm_sp(
    const float* __restrict__ A, const ushort* __restrict__ BTh,
    const float* __restrict__ bias, float* __restrict__ C,
    int M, int N, int K,
    const float* __restrict__ addsrc, float* __restrict__ out2)
{
    __shared__ __align__(16) ushort Ah[2][64 * 40];
    __shared__ __align__(16) ushort Al[2][64 * 40];
    __shared__ __align__(16) ushort Bh[2][64 * 32];

    const int tid  = threadIdx.x;
    const int m0   = blockIdx.x * 64;
    const int n0   = blockIdx.y * 64;
    const int wv   = tid >> 6;
    const int lane = tid & 63;
    const int lm   = lane & 15;
    const int lq   = lane >> 4;
    const int r    = tid >> 2;
    const int c8   = (tid & 3) * 8;

    // ---- prologue: stage tile 0 ----
    {
        float av[8];
        if (32 <= K) {
            *(float4*)&av[0] = *(const float4*)&A[(size_t)(m0 + r) * K + c8];
            *(float4*)&av[4] = *(const float4*)&A[(size_t)(m0 + r) * K + c8 + 4];
        } else {
#pragma unroll
            for (int j = 0; j < 8; ++j) {
                int k = c8 + j;
                av[j] = (k < K) ? A[(size_t)(m0 + r) * K + k] : 0.f;
            }
        }
        us8 hv, lv;
#pragma unroll
        for (int j = 0; j < 8; ++j) {
            ushort h, l;
            split2(av[j], h, l);
            hv[j] = h; lv[j] = l;
        }
        *(us8*)&Ah[0][r * 40 + c8] = hv;
        *(us8*)&Al[0][r * 40 + c8] = lv;
        // B tile 0 async (LDS offset = tid*16B = wave base + lane*16)
        gl_lds16(&BTh[(size_t)(n0 + r) * K + c8], &Bh[0][r * 32 + c8]);
    }
    __syncthreads();

    f32x4 acc[4] = {};
    int buf = 0;
    for (int k0 = 32; k0 < K + 32; k0 += 32) {
        const int nxt = buf ^ 1;
        const bool has = (k0 < K);   // K%32==0 for all K>32 call sites
        float av[8];
        if (has) {
            gl_lds16(&BTh[(size_t)(n0 + r) * K + k0 + c8], &Bh[nxt][r * 32 + c8]);
            *(float4*)&av[0] = *(const float4*)&A[(size_t)(m0 + r) * K + k0 + c8];
            *(float4*)&av[4] = *(const float4*)&A[(size_t)(m0 + r) * K + k0 + c8 + 4];
        }

        bf16x8 afh = *(const bf16x8*)&Ah[buf][(wv * 16 + lm) * 40 + lq * 8];
        bf16x8 afl = *(const bf16x8*)&Al[buf][(wv * 16 + lm) * 40 + lq * 8];
#pragma unroll
        for (int nb = 0; nb < 4; ++nb) {
            bf16x8 bfh = *(const bf16x8*)&Bh[buf][(nb * 16 + lm) * 32 + lq * 8];
            acc[nb] = __builtin_amdgcn_mfma_f32_16x16x32_bf16(afh, bfh, acc[nb], 0, 0, 0);
            acc[nb] = __builtin_amdgcn_mfma_f32_16x16x32_bf16(afl, bfh, acc[nb], 0, 0, 0);
        }

        if (has) {
            us8 hv, lv;
#pragma unroll
            for (int j = 0; j < 8; ++j) {
                ushort h, l;
                split2(av[j], h, l);
                hv[j] = h; lv[j] = l;
            }
            *(us8*)&Ah[nxt][r * 40 + c8] = hv;
            *(us8*)&Al[nxt][r * 40 + c8] = lv;
            __syncthreads();
        }
        buf = nxt;
    }

    const int row = m0 + wv * 16 + lq * 4;
#pragma unroll
    for (int nb = 0; nb < 4; ++nb) {
        int col = n0 + nb * 16 + lm;
        if (col < N) {
            float bv = bias ? bias[col] : 0.f;
#pragma unroll
            for (int rr = 0; rr < 4; ++rr) {
                float v = acc[nb][rr] + bv;
                if (ACT) v = fmaxf(v, 0.f);
                const size_t idx = (size_t)(row + rr) * N + col;
                C[idx] = v;
                if (out2) out2[idx] = v + addsrc[idx];
            }
        }
    }
}

// ---------------------------------------------------------------------------
// Fat-tile bf16 GEMM (128x128, 4 waves, 4x4 acc): C bf16 = Abf @ BTh^T + bias.
// ---------------------------------------------------------------------------
__global__ __launch_bounds__(256) void gemm_big(
    const ushort* __restrict__ Abf, const ushort* __restrict__ BTh,
    const float* __restrict__ bias, ushort* __restrict__ C,
    int M, int N, int K)
{
    __shared__ __align__(16) ushort As[128 * 32];
    __shared__ __align__(16) ushort Bs[128 * 32];
    const int tid = threadIdx.x;
    const int n0 = blockIdx.x * 128, m0 = blockIdx.y * 128;
    const int wv = tid >> 6, lane = tid & 63;
    const int lm = lane & 15, quad = lane >> 4;
    const int wr = wv >> 1, wc = wv & 1;
    const int srow = lane >> 2;
    const int scol = (lane & 3) * 8;

    f32x4 acc[4][4] = {};

    for (int k0 = 0; k0 < K; k0 += 32) {
        __syncthreads();
#pragma unroll
        for (int s2 = 0; s2 < 2; ++s2) {
            const int seg = wv * 2 + s2;
            const int row = seg * 16 + srow;
            gl_lds16(&Abf[(size_t)(m0 + row) * K + k0 + scol],
                     &As[seg * 512 + lane * 8]);
            gl_lds16(&BTh[(size_t)(n0 + row) * K + k0 + scol],
                     &Bs[seg * 512 + lane * 8]);
        }
        __syncthreads();

        bf16x8 af[4], bfr[4];
#pragma unroll
        for (int i = 0; i < 4; ++i)
            af[i] = *(const bf16x8*)&As[(wr * 64 + i * 16 + lm) * 32 + quad * 8];
#pragma unroll
        for (int i = 0; i < 4; ++i)
            bfr[i] = *(const bf16x8*)&Bs[(wc * 64 + i * 16 + lm) * 32 + quad * 8];
#pragma unroll
        for (int mi = 0; mi < 4; ++mi)
#pragma unroll
            for (int ni = 0; ni < 4; ++ni)
                acc[mi][ni] = __builtin_amdgcn_mfma_f32_16x16x32_bf16(
                    af[mi], bfr[ni], acc[mi][ni], 0, 0, 0);
    }

#pragma unroll
    for (int ni = 0; ni < 4; ++ni) {
        const int col = n0 + wc * 64 + ni * 16 + lm;
        const float bv = bias[col];
#pragma unroll
        for (int mi = 0; mi < 4; ++mi) {
            const int row = m0 + wr * 64 + mi * 16 + quad * 4;
#pragma unroll
            for (int rr = 0; rr < 4; ++rr)
                C[(size_t)(row + rr) * N + col] = f2b(acc[mi][ni][rr] + bv);
        }
    }
}

// ---------------------------------------------------------------------------
// MFMA MHA: one block per (b, h, q-half); strided q/k/v.
// ---------------------------------------------------------------------------
__global__ __launch_bounds__(256) void mha_mfma_kernel(
    const float* __restrict__ qh, int ldq, const float* __restrict__ kh, int ldk,
    const float* __restrict__ vh, int ldv, float* __restrict__ outp)
{
    __shared__ ushort Kh[304 * 36];
    __shared__ ushort Vth[32 * 328];
    __shared__ ushort Pb[4][16 * 168];

    const int tid = threadIdx.x;
    const int wv = tid >> 6, lane = tid & 63;
    const int bh = blockIdx.x >> 1, half = blockIdx.x & 1;
    const int b = bh >> 3, h = bh & 7;
    const size_t qbase = (size_t)b * NQL * ldq + h * HDIM;
    const size_t kbase = (size_t)b * NQL * ldk + h * HDIM;
    const size_t vbase = (size_t)b * NQL * ldv + h * HDIM;
    const size_t obase = (size_t)b * NQL * DM + h * HDIM;

    for (int idx = tid; idx < 304 * 32; idx += 256) {
        int row = idx >> 5, d = idx & 31;
        float v = (row < NQL) ? kh[kbase + (size_t)row * ldk + d] : 0.f;
        Kh[row * 36 + d] = f2b(v);
    }
    for (int idx = tid; idx < 328 * 32; idx += 256) {
        int key = idx >> 5, d = idx & 31;
        float v = (key < NQL) ? vh[vbase + (size_t)key * ldv + d] : 0.f;
        Vth[d * 328 + key] = f2b(v);
    }
    for (int i = lane; i < 16 * 168; i += 64) Pb[wv][i] = 0;
    __syncthreads();

    const int quad = lane >> 4, c = lane & 15;
    const float scale = 0.17677669529663687f;

    const int qt_beg = (half ? 10 : 0) + wv;
    const int qt_end = (half ? 19 : 10);
    for (int qt = qt_beg; qt < qt_end; qt += 4) {
        const int q = qt * 16 + c;
        const float* qrow = qh + qbase + (size_t)q * ldq + quad * 8;
        float qv[8];
        *(float4*)&qv[0] = *(const float4*)qrow;
        *(float4*)&qv[4] = *(const float4*)(qrow + 4);
        bf16x8 qf;
#pragma unroll
        for (int j = 0; j < 8; ++j) ((ushort*)&qf)[j] = f2b(qv[j]);

        f32x4 sc[19];
#pragma unroll
        for (int kt = 0; kt < 19; ++kt) {
            bf16x8 kf = *(const bf16x8*)&Kh[(kt * 16 + c) * 36 + quad * 8];
            f32x4 a = {};
            a = __builtin_amdgcn_mfma_f32_16x16x32_bf16(qf, kf, a, 0, 0, 0);
            sc[kt] = a;
        }
        float inv4[4];
#pragma unroll
        for (int r = 0; r < 4; ++r) {
            float mx = -1e30f;
#pragma unroll
            for (int kt = 0; kt < 19; ++kt) {
                float s = sc[kt][r] * scale;
                if (kt * 16 + c >= NQL) s = -1e30f;
                sc[kt][r] = s;
                mx = fmaxf(mx, s);
            }
#pragma unroll
            for (int m = 1; m < 16; m <<= 1) mx = fmaxf(mx, __shfl_xor(mx, m, 64));
            float l = 0.f;
#pragma unroll
            for (int kt = 0; kt < 19; ++kt) {
                float p = __expf(sc[kt][r] - mx);
                sc[kt][r] = p;
                l += p;
            }
#pragma unroll
            for (int m = 1; m < 16; m <<= 1) l += __shfl_xor(l, m, 64);
            inv4[r] = 1.f / l;
        }

        f32x4 o0 = {}, o1 = {};
#pragma unroll
        for (int r = 0; r < 4; ++r)
#pragma unroll
            for (int kt = 0; kt < 10; ++kt)
                Pb[wv][(quad * 4 + r) * 168 + kt * 16 + c] = f2b(sc[kt][r] * inv4[r]);
#pragma unroll
        for (int ks = 0; ks < 5; ++ks) {
            bf16x8 pf = *(const bf16x8*)&Pb[wv][c * 168 + ks * 32 + quad * 8];
            bf16x8 v0 = *(const bf16x8*)&Vth[c * 328 + ks * 32 + quad * 8];
            bf16x8 v1 = *(const bf16x8*)&Vth[(16 + c) * 328 + ks * 32 + quad * 8];
            o0 = __builtin_amdgcn_mfma_f32_16x16x32_bf16(pf, v0, o0, 0, 0, 0);
            o1 = __builtin_amdgcn_mfma_f32_16x16x32_bf16(pf, v1, o1, 0, 0, 0);
        }
#pragma unroll
        for (int r = 0; r < 4; ++r) {
#pragma unroll
            for (int kt = 10; kt < 19; ++kt)
                Pb[wv][(quad * 4 + r) * 168 + (kt - 10) * 16 + c] = f2b(sc[kt][r] * inv4[r]);
            Pb[wv][(quad * 4 + r) * 168 + 144 + c] = 0;
        }
#pragma unroll
        for (int ks = 0; ks < 5; ++ks) {
            bf16x8 pf = *(const bf16x8*)&Pb[wv][c * 168 + ks * 32 + quad * 8];
            bf16x8 v0 = *(const bf16x8*)&Vth[c * 328 + 160 + ks * 32 + quad * 8];
            bf16x8 v1 = *(const bf16x8*)&Vth[(16 + c) * 328 + 160 + ks * 32 + quad * 8];
            o0 = __builtin_amdgcn_mfma_f32_16x16x32_bf16(pf, v0, o0, 0, 0, 0);
            o1 = __builtin_amdgcn_mfma_f32_16x16x32_bf16(pf, v1, o1, 0, 0, 0);
        }
#pragma unroll
        for (int r = 0; r < 4; ++r) {
            const int qq = qt * 16 + quad * 4 + r;
            if (qq < NQL) {
                outp[obase + (size_t)qq * DM + c] = o0[r];
                outp[obase + (size_t)qq * DM + 16 + c] = o1[r];
            }
        }
    }
}

// ---------------------------------------------------------------------------
// Deformable sampling. offaw: per row 288 = 192 offsets + 96 aw logits.
// ---------------------------------------------------------------------------
__global__ __launch_bounds__(256) void deform_kernel(
    const ushort* __restrict__ val, const float* __restrict__ offaw,
    const float* __restrict__ refd, float* __restrict__ outp)
{
    __shared__ float offs[192];
    __shared__ float aws[96];
    __shared__ float rr[4];
    const int row = blockIdx.x;
    const int b = row / NQL;
    const int t = threadIdx.x;
    if (t < 192) offs[t] = offaw[(size_t)row * 288 + t];
    if (t < 96)  aws[t] = offaw[(size_t)row * 288 + 192 + t];
    if (t < 4)   rr[t] = refd[row * 4 + t];
    __syncthreads();

    const int h = t >> 5, d = t & 31;
    float mx = -1e30f;
#pragma unroll
    for (int j = 0; j < 12; ++j) mx = fmaxf(mx, aws[h * 12 + j]);
    float ev[12]; float se = 0.f;
#pragma unroll
    for (int j = 0; j < 12; ++j) { ev[j] = __expf(aws[h * 12 + j] - mx); se += ev[j]; }
    const float inv = 1.f / se;

    const int HWs[3] = {80, 40, 20};
    const int STs[3] = {0, 6400, 8000};
    float acc = 0.f;
#pragma unroll
    for (int l = 0; l < NLVL; ++l) {
        const int Wd = HWs[l], Hd = HWs[l], st = STs[l];
#pragma unroll
        for (int p = 0; p < NPT; ++p) {
            const float w12 = ev[l * 4 + p] * inv;
            const float ox = offs[((h * 3 + l) * 4 + p) * 2 + 0];
            const float oy = offs[((h * 3 + l) * 4 + p) * 2 + 1];
            const float x = (rr[0] + ox * 0.125f * rr[2]) * Wd - 0.5f;
            const float y = (rr[1] + oy * 0.125f * rr[3]) * Hd - 0.5f;
            const float xf = floorf(x), yf = floorf(y);
            const int x0 = (int)xf, y0 = (int)yf;
            const float wx = x - xf, wy = y - yf;
            const float tw[4] = {(1 - wx) * (1 - wy), wx * (1 - wy),
                                 (1 - wx) * wy,       wx * wy};
            const int xs[4] = {x0, x0 + 1, x0, x0 + 1};
            const int ys[4] = {y0, y0, y0 + 1, y0 + 1};
            float sv = 0.f;
#pragma unroll
            for (int tp = 0; tp < 4; ++tp) {
                const int xi = xs[tp], yi = ys[tp];
                if (xi >= 0 && xi < Wd && yi >= 0 && yi < Hd) {
                    const int idx = st + yi * Wd + xi;
                    sv += tw[tp] * b2f(val[((size_t)b * LVTOT + idx) * DM + h * HDIM + d]);
                }
            }
            acc += w12 * sv;
        }
    }
    outp[(size_t)row * DM + t] = acc;
}

// ---------------------------------------------------------------------------
// Fused residual add + LayerNorm (fp32). One wave per row.
// ---------------------------------------------------------------------------
__global__ __launch_bounds__(256) void addln_kernel(
    const float* x, const float* __restrict__ dl,
    const float* __restrict__ g, const float* __restrict__ bb,
    float* outf, const float* __restrict__ qpos, float* __restrict__ q2)
{
    const int wv = threadIdx.x >> 6, lane = threadIdx.x & 63;
    const int row = blockIdx.x * 4 + wv;
    const size_t base = (size_t)row * DM + lane * 4;
    const float4 xv = *(const float4*)(x + base);
    const float4 dv = *(const float4*)(dl + base);
    float v[4] = {xv.x + dv.x, xv.y + dv.y, xv.z + dv.z, xv.w + dv.w};

    float s = v[0] + v[1] + v[2] + v[3];
#pragma unroll
    for (int m = 32; m; m >>= 1) s += __shfl_xor(s, m, 64);
    const float mean = s * (1.f / 256.f);
    float sq = 0.f;
#pragma unroll
    for (int j = 0; j < 4; ++j) { float dd = v[j] - mean; sq += dd * dd; }
#pragma unroll
    for (int m = 32; m; m >>= 1) sq += __shfl_xor(sq, m, 64);
    const float rstd = rsqrtf(sq * (1.f / 256.f) + 1e-5f);

    float y[4];
#pragma unroll
    for (int j = 0; j < 4; ++j) {
        const int col = lane * 4 + j;
        y[j] = (v[j] - mean) * rstd * g[col] + bb[col];
    }
    *(float4*)(outf + base) = make_float4(y[0], y[1], y[2], y[3]);
    if (q2) {
        const float4 qp = *(const float4*)(qpos + base);
        *(float4*)(q2 + base) = make_float4(y[0] + qp.x, y[1] + qp.y,
                                            y[2] + qp.z, y[3] + qp.w);
    }
}

// ---------------------------------------------------------------------------
// Small elementwise kernels
// ---------------------------------------------------------------------------
__global__ __launch_bounds__(256) void init_ref_kernel(
    const float* __restrict__ rpu, float* __restrict__ refd, int n)
{
    int i = blockIdx.x * 256 + threadIdx.x;
    if (i < n) refd[i] = 1.f / (1.f + __expf(-rpu[i]));
}

__global__ __launch_bounds__(256) void refupd_kernel(
    const float* __restrict__ b3, float* __restrict__ refd,
    float* __restrict__ dout, int writeout)
{
    int i = blockIdx.x * 256 + threadIdx.x;
    if (i < NROW * 4) {
        float r = fminf(fmaxf(refd[i], 0.f), 1.f);
        float invs = logf(fmaxf(r, 1e-5f)) - logf(fmaxf(1.f - r, 1e-5f));
        float v = 1.f / (1.f + __expf(-(b3[i] + invs)));
        refd[i] = v;
        if (writeout) dout[i] = v;
    }
}

// ---------------------------------------------------------------------------
// Host launch
// ---------------------------------------------------------------------------
extern "C" void kernel_launch(void* const* d_in, const int* in_sizes, int n_in,
                              void* d_out, int out_size, void* d_ws, size_t ws_size,
                              hipStream_t stream)
{
    const float* tgt    = (const float*)d_in[0];
    const float* rpu    = (const float*)d_in[1];
    const float* memory = (const float*)d_in[2];
    const float* Wq  = (const float*)d_in[5];  const float* bq  = (const float*)d_in[6];
    const float* Wk  = (const float*)d_in[7];  const float* bk  = (const float*)d_in[8];
    const float* Wv  = (const float*)d_in[9];  const float* bv  = (const float*)d_in[10];
    const float* Wo  = (const float*)d_in[11]; const float* bo  = (const float*)d_in[12];
    const float* ln1g = (const float*)d_in[13]; const float* ln1b = (const float*)d_in[14];
    const float* ln2g = (const float*)d_in[15]; const float* ln2b = (const float*)d_in[16];
    const float* ln3g = (const float*)d_in[17]; const float* ln3b = (const float*)d_in[18];
    const float* Wvp = (const float*)d_in[19]; const float* bvp = (const float*)d_in[20];
    const float* Woff = (const float*)d_in[21]; const float* boff = (const float*)d_in[22];
    const float* Waw = (const float*)d_in[23]; const float* baw = (const float*)d_in[24];
    const float* Wop = (const float*)d_in[25]; const float* bop = (const float*)d_in[26];
    const float* Wff1 = (const float*)d_in[27]; const float* bff1 = (const float*)d_in[28];
    const float* Wff2 = (const float*)d_in[29]; const float* bff2 = (const float*)d_in[30];
    const float* Wb1 = (const float*)d_in[31]; const float* bb1 = (const float*)d_in[32];
    const float* Wb2 = (const float*)d_in[33]; const float* bb2 = (const float*)d_in[34];
    const float* Wb3 = (const float*)d_in[35]; const float* bb3 = (const float*)d_in[36];
    const float* Ws  = (const float*)d_in[37]; const float* bs_ = (const float*)d_in[38];
    const float* Wp1 = (const float*)d_in[39]; const float* bp1 = (const float*)d_in[40];
    const float* Wp2 = (const float*)d_in[41]; const float* bp2 = (const float*)d_in[42];

    size_t off = 0;
    auto alloc = [&](size_t elems, size_t elsz) -> void* {
        void* r = (char*)d_ws + off;
        off += elems * elsz;
        off = (off + 255) & ~(size_t)255;
        return r;
    };
    ushort *wqkh = (ushort*)alloc(6 * 131072, 2);
    ushort *wvh  = (ushort*)alloc(6 * 65536, 2);
    ushort *woh  = (ushort*)alloc(6 * 65536, 2);
    ushort *wvph = (ushort*)alloc(6 * 65536, 2);
    ushort *wfah = (ushort*)alloc(6 * 81920, 2);
    ushort *woph = (ushort*)alloc(6 * 65536, 2);
    ushort *wf1h = (ushort*)alloc(6 * 262144, 2);
    ushort *wf2h = (ushort*)alloc(6 * 262144, 2);
    ushort *wb1h = (ushort*)alloc(6 * 65536, 2);
    ushort *wb2h = (ushort*)alloc(6 * 65536, 2);
    ushort *wb3h = (ushort*)alloc(6 * 1024, 2);
    ushort *wsh  = (ushort*)alloc(6 * 20480, 2);
    ushort *wp1h = (ushort*)alloc(2048, 2);
    ushort *wp2h = (ushort*)alloc(131072, 2);
    float  *bqk  = (float*)alloc(6 * 512, 4);
    float  *bfa  = (float*)alloc(6 * 288, 4);

    ushort* mem_bf = (ushort*)alloc((size_t)MEMN * DM, 2);   // 68.8 MB
    ushort* val_bf = (ushort*)alloc((size_t)MEMN * DM, 2);   // 68.8 MB
    float*  out_f  = (float*)alloc(NROW * DM, 4);
    float*  qpos_f = (float*)alloc(NROW * DM, 4);
    float*  q_f    = (float*)alloc(NROW * DM, 4);
    float*  q2_f   = (float*)alloc(NROW * DM, 4);
    float*  tmp_f  = (float*)alloc(NROW * DM, 4);
    float*  b3_f   = (float*)alloc(NROW * 4, 4);
    float*  refd_f = (float*)alloc(NROW * 4, 4);
    float* arena = (float*)alloc(NROW * 1024, 4);
    float* t1_f    = arena;
    float* qk_f    = arena;
    float* vh_f    = arena + NROW * 512;
    float* att_f   = arena + NROW * 768;
    float* offaw_f = arena;
    float* samp_f  = arena + NROW * 288;
    float* ff_f    = arena;
    float* h1_f    = arena;
    float* h2_f    = arena + NROW * DM;

    if (off > ws_size) return;

    dim3 tb(32, 8);
    auto T = [&](const float* s, ushort* dh, int K, int N, int B, int dls, int dr0) {
        dim3 g((N + 31) / 32, (K + 31) / 32, B);
        transpose_split_kernel<<<g, tb, 0, stream>>>(s, dh, K, N, dls, dr0);
    };
    T(Wq, wqkh, 256, 256, 6, 131072, 0);
    T(Wk, wqkh, 256, 256, 6, 131072, 256);
    T(Wv, wvh, 256, 256, 6, 65536, 0);
    T(Wo, woh, 256, 256, 6, 65536, 0);
    T(Wvp, wvph, 256, 256, 6, 65536, 0);
    T(Woff, wfah, 256, 192, 6, 81920, 0);
    T(Waw, wfah, 256, 96, 6, 81920, 192);
    T(Wop, woph, 256, 256, 6, 65536, 0);
    T(Wff1, wf1h, 256, 1024, 6, 262144, 0);
    T(Wff2, wf2h, 1024, 256, 6, 262144, 0);
    T(Wb1, wb1h, 256, 256, 6, 65536, 0);
    T(Wb2, wb2h, 256, 256, 6, 65536, 0);
    T(Wb3, wb3h, 256, 4, 6, 1024, 0);
    T(Ws, wsh, 256, 80, 6, 20480, 0);
    T(Wp1, wp1h, 4, 512, 1, 131072, 0);
    T(Wp2, wp2h, 512, 256, 1, 131072, 0);
    concat2_kernel<<<12, 256, 0, stream>>>(bq, 256, bk, 256, bqk, 6);
    concat2_kernel<<<7, 256, 0, stream>>>(boff, 192, baw, 96, bfa, 6);
    f2b_kernel<<<(MEMN * DM) / 1024, 256, 0, stream>>>(memory, mem_bf, MEMN * DM);

    hipMemcpyAsync(out_f, tgt, (size_t)NROW * DM * 4, hipMemcpyDeviceToDevice, stream);
    init_ref_kernel<<<75, 256, 0, stream>>>(rpu, refd_f, NROW * 4);

    auto G = [&](const float* A, const ushort* BTh, const float* bias,
                 float* C, int M, int N, int K, bool relu,
                 const float* addsrc = nullptr, float* out2 = nullptr) {
        dim3 g(M / 64, (N + 63) / 64);
        if (relu) gemm_sp<1><<<g, 256, 0, stream>>>(A, BTh, bias, C, M, N, K, addsrc, out2);
        else      gemm_sp<0><<<g, 256, 0, stream>>>(A, BTh, bias, C, M, N, K, addsrc, out2);
    };

    for (int i = 0; i < NLAYERS; ++i) {
        // qpos = relu(ref_d @ Wp1 + bp1) @ Wp2 + bp2;  q = out + qpos (fused)
        G(refd_f, wp1h, bp1, t1_f, NROW, 512, 4, true);
        G(t1_f, wp2h, bp2, qpos_f, NROW, 256, 512, false, out_f, q_f);
        // MHA (Q|K fused)
        G(q_f, wqkh + i * 131072, bqk + i * 512, qk_f, NROW, 512, 256, false);
        G(out_f, wvh + i * 65536, bv + i * 256, vh_f, NROW, 256, 256, false);
        mha_mfma_kernel<<<256, 256, 0, stream>>>(qk_f, 512, qk_f + 256, 512, vh_f, 256, att_f);
        G(att_f, woh + i * 65536, bo + i * 256, tmp_f, NROW, 256, 256, false);
        addln_kernel<<<1200, 256, 0, stream>>>(out_f, tmp_f, ln1g + i * 256, ln1b + i * 256,
                                               out_f, qpos_f, q2_f);
        // Deformable attention: fat-tile bf16 value projection
        {
            dim3 g(DM / 128, MEMN / 128);
            gemm_big<<<g, 256, 0, stream>>>(mem_bf, wvph + i * 65536, bvp + i * 256,
                                            val_bf, MEMN, DM, DM);
        }
        G(q2_f, wfah + i * 81920, bfa + i * 288, offaw_f, NROW, 288, 256, false);
        deform_kernel<<<4800, 256, 0, stream>>>(val_bf, offaw_f, refd_f, samp_f);
        G(samp_f, woph + i * 65536, bop + i * 256, tmp_f, NROW, 256, 256, false);
        addln_kernel<<<1200, 256, 0, stream>>>(out_f, tmp_f, ln2g + i * 256, ln2b + i * 256,
                                               out_f, nullptr, nullptr);
        // FFN
        G(out_f, wf1h + i * 262144, bff1 + i * 1024, ff_f, NROW, 1024, 256, true);
        G(ff_f, wf2h + i * 262144, bff2 + i * 256, tmp_f, NROW, 256, 1024, false);
        addln_kernel<<<1200, 256, 0, stream>>>(out_f, tmp_f, ln3g + i * 256, ln3b + i * 256,
                                               out_f, nullptr, nullptr);
        // bbox head
        G(out_f, wb1h + i * 65536, bb1 + i * 256, h1_f, NROW, 256, 256, true);
        G(h1_f, wb2h + i * 65536, bb2 + i * 256, h2_f, NROW, 256, 256, true);
        G(h2_f, wb3h + i * 1024, bb3 + i * 4, b3_f, NROW, 4, 256, false);
        refupd_kernel<<<75, 256, 0, stream>>>(b3_f, refd_f, (float*)d_out,
                                              (i == NLAYERS - 1) ? 1 : 0);
        if (i == NLAYERS - 1) {
            G(out_f, wsh + i * 20480, bs_ + i * 80,
              (float*)d_out + NROW * 4, NROW, 80, 256, false);
        }
    }
}